// Round 10
// baseline (488.580 us; speedup 1.0000x reference)
//
#include <hip/hip_runtime.h>
#include <stdint.h>
#include <math.h>

// ---------------- types ----------------
typedef __attribute__((ext_vector_type(4))) float f32x4;
typedef __attribute__((ext_vector_type(8))) short s16x8;   // 8 x bf16 (4 VGPRs)
typedef __attribute__((ext_vector_type(4))) unsigned short u16x4;

__device__ __forceinline__ unsigned short f2b(float x) {
    union { float f; uint32_t u; } v; v.f = x;
    uint32_t r = v.u + 0x7FFFu + ((v.u >> 16) & 1u);   // round-to-nearest-even
    return (unsigned short)(r >> 16);
}
__device__ __forceinline__ float b2f(unsigned short u) {
    union { uint32_t u; float f; } v; v.u = (uint32_t)u << 16;
    return v.f;
}

__device__ __forceinline__ void gload16(const unsigned short* g, unsigned short* l) {
    __builtin_amdgcn_global_load_lds(
        (const __attribute__((address_space(1))) unsigned int*)(const void*)g,
        (__attribute__((address_space(3))) unsigned int*)(void*)l,
        16, 0, 0);
}

// ---------------- fused fp32 -> bf16 cast of the 4 weight tensors ----------------
__global__ __launch_bounds__(256) void cast4_kernel(
        const float* __restrict__ a, int na, const float* __restrict__ b, int nb,
        const float* __restrict__ c, int nc, const float* __restrict__ d, int nd,
        unsigned short* __restrict__ oa, unsigned short* __restrict__ ob,
        unsigned short* __restrict__ oc, unsigned short* __restrict__ od) {
    int i = blockIdx.x * 256 + threadIdx.x;
    const float* src; unsigned short* dst; int off;
    if (i < na)                { src = a; dst = oa; off = i; }
    else if (i < na+nb)        { src = b; dst = ob; off = i - na; }
    else if (i < na+nb+nc)     { src = c; dst = oc; off = i - na - nb; }
    else if (i < na+nb+nc+nd)  { src = d; dst = od; off = i - na - nb - nc; }
    else return;
    f32x4 v = ((const f32x4*)src)[off];
    u16x4 o;
    #pragma unroll
    for (int j = 0; j < 4; ++j) o[j] = f2b(v[j]);
    ((u16x4*)dst)[off] = o;
}

// ---------------- LayerNorm (C=1024), fp32 in -> bf16 out ----------------
__global__ __launch_bounds__(256) void ln_kernel(const float* __restrict__ x,
                                                 const float* __restrict__ w,
                                                 const float* __restrict__ b,
                                                 unsigned short* __restrict__ out) {
    const long row = blockIdx.x;
    const int tid = threadIdx.x;
    f32x4 v = *(const f32x4*)(x + row * 1024 + tid * 4);
    float s  = v[0] + v[1] + v[2] + v[3];
    float sq = v[0]*v[0] + v[1]*v[1] + v[2]*v[2] + v[3]*v[3];
    #pragma unroll
    for (int off = 32; off; off >>= 1) {
        s  += __shfl_xor(s, off);
        sq += __shfl_xor(sq, off);
    }
    __shared__ float red[8];
    if ((tid & 63) == 0) { red[tid >> 6] = s; red[4 + (tid >> 6)] = sq; }
    __syncthreads();
    s  = red[0] + red[1] + red[2] + red[3];
    sq = red[4] + red[5] + red[6] + red[7];
    float mu  = s * (1.0f / 1024.0f);
    float var = sq * (1.0f / 1024.0f) - mu * mu;
    float rs  = rsqrtf(var + 1e-5f);
    f32x4 wv = *(const f32x4*)(w + tid * 4);
    f32x4 bv = *(const f32x4*)(b + tid * 4);
    u16x4 o;
    #pragma unroll
    for (int j = 0; j < 4; ++j) o[j] = f2b((v[j] - mu) * rs * wv[j] + bv[j]);
    *(u16x4*)(out + row * 1024 + tid * 4) = o;
}

// ---------------- psum[row][16] -> invl[row] = 1/sum ----------------
__global__ __launch_bounds__(256) void inv_kernel(const float* __restrict__ psum,
                                                  float* __restrict__ invl) {
    const long r = blockIdx.x * 256 + threadIdx.x;       // 65536 rows
    const float* p = psum + (r << 4);
    f32x4 a = *(const f32x4*)p,       b = *(const f32x4*)(p + 4);
    f32x4 c = *(const f32x4*)(p + 8), d = *(const f32x4*)(p + 12);
    float s = (a[0]+a[1]+a[2]+a[3]) + (b[0]+b[1]+b[2]+b[3])
            + (c[0]+c[1]+c[2]+c[3]) + (d[0]+d[1]+d[2]+d[3]);
    invl[r] = 1.0f / s;
}

// ---------------- fused PV + att-write (round-8 proven) ----------------
__global__ __launch_bounds__(256)
void pv_att(const unsigned short* __restrict__ E,    // [64][1024][1024] bf16 exp
            const unsigned short* __restrict__ Vt,   // [64][64][1024] bf16 (d-major)
            const float* __restrict__ invl,          // [64][1024]
            float* __restrict__ att,                 // [64][1024][1024] fp32
            unsigned short* __restrict__ y) {        // [4096][1024] bf16 scatter
    __shared__ unsigned short ldsA[3][64 * 32];
    __shared__ unsigned short ldsB[3][64 * 32];
    const int tid = threadIdx.x, lane = tid & 63, wid = tid >> 6;
    const int wr = wid >> 1, wc = wid & 1;
    const int bh = blockIdx.y;
    const int q0 = blockIdx.x * 64;
    const int fr = lane & 15, fs = lane >> 4;

    const unsigned short* Ab = E + ((long)bh << 20) + (long)q0 * 1024;
    const unsigned short* Bb = Vt + ((long)bh << 16);

    const int e0  = wid * 512 + lane * 8;
    const int r0a = e0 >> 5, c0a = e0 & 31;      // this thread's staged row/col
    const float il_a = invl[(bh << 10) + q0 + r0a];
    float* attRow = att + ((long)bh << 20) + (long)(q0 + r0a) * 1024 + c0a;

    f32x4 acc[2][2] = {};

#define PSTAGE(T, BUF)                                                        \
    {                                                                         \
        const int k0s = (T) << 5;                                             \
        gload16(Ab + k0s + (long)r0a * 1024 + c0a, &ldsA[BUF][wid * 512]);    \
        gload16(Bb + k0s + (long)r0a * 1024 + c0a, &ldsB[BUF][wid * 512]);    \
    }

    PSTAGE(0, 0);
    PSTAGE(1, 1);

    for (int t = 0; t < 32; ++t) {
        const int buf = t % 3;
        asm volatile("s_waitcnt vmcnt(4)" ::: "memory");
        __syncthreads();
        if (t + 2 < 32) PSTAGE(t + 2, (t + 2) % 3);

        // att write from staged tile (own 8 elems)
        {
            s16x8 ea = *(const s16x8*)&ldsA[buf][e0];
            f32x4 o0, o1;
            #pragma unroll
            for (int j = 0; j < 4; ++j) o0[j] = b2f((unsigned short)ea[j]) * il_a;
            #pragma unroll
            for (int j = 0; j < 4; ++j) o1[j] = b2f((unsigned short)ea[4 + j]) * il_a;
            *(f32x4*)(attRow + t * 32)     = o0;
            *(f32x4*)(attRow + t * 32 + 4) = o1;
        }

        s16x8 af[2], vb[2];
        #pragma unroll
        for (int m = 0; m < 2; ++m)
            af[m] = *(const s16x8*)&ldsA[buf][(wr * 32 + m * 16 + fr) * 32 + fs * 8];
        #pragma unroll
        for (int n = 0; n < 2; ++n)
            vb[n] = *(const s16x8*)&ldsB[buf][(wc * 32 + n * 16 + fr) * 32 + fs * 8];
        #pragma unroll
        for (int m = 0; m < 2; ++m)
            #pragma unroll
            for (int n = 0; n < 2; ++n)
                acc[m][n] = __builtin_amdgcn_mfma_f32_16x16x32_bf16(af[m], vb[n], acc[m][n], 0, 0, 0);
    }
#undef PSTAGE

    // y scatter: [B,T,C] bf16, scaled by invl of the output row
    const int bb = bh >> 4, hh = bh & 15;
    #pragma unroll
    for (int m = 0; m < 2; ++m) {
        #pragma unroll
        for (int r = 0; r < 4; ++r) {
            const int trow = q0 + wr * 32 + m * 16 + fs * 4 + r;
            const float il = invl[(bh << 10) + trow];
            #pragma unroll
            for (int n = 0; n < 2; ++n) {
                const int c = hh * 64 + wc * 32 + n * 16 + fr;
                y[((long)(bb * 1024 + trow) << 10) + c] = f2b(acc[m][n][r] * il);
            }
        }
    }
}

// ---------------- 256x256 GEMM: 2-phase proven structure scaled up, 512 threads --------
// 2 LDS bufs (64 KB), depth-1 prefetch, vmcnt(4), 2 barriers/K-step, XCD-chunk swizzle.
// 1D grid, y = col-tile decoded fastest-shared (same-XCD blocks share B panel).
// EPI: 0 = QKV scatter, 4 = bias+GELU->bf16
template <int EPI>
__global__ __launch_bounds__(512, 2)
void gemm256(const unsigned short* __restrict__ A,
             const unsigned short* __restrict__ Bm,
             int K, int lda, int ldb, int ldc, int nx,
             const float* __restrict__ bias,
             unsigned short* __restrict__ outB) {
    __shared__ unsigned short ldsA[2][8192];
    __shared__ unsigned short ldsB[2][8192];
    const int tid = threadIdx.x, lane = tid & 63, wid = tid >> 6;
    const int wr = wid >> 2, wcn = wid & 3;          // 2M x 4N waves
    const int fr = lane & 15, kg = lane >> 4;

    // XCD-chunk swizzle (bijective; gridDim.x % 8 == 0)
    const int nwg = gridDim.x, q = nwg >> 3, n = blockIdx.x;
    const int m0 = (n & 7) * q + (n >> 3);
    const int bx = m0 % nx, by = m0 / nx;
    const int row0 = bx * 256, col0 = by * 256;

    const unsigned short* Ab = A + (long)row0 * lda;
    const unsigned short* Bb = Bm + (long)col0 * ldb;
    const int nt = K >> 5;

    const int e0 = tid * 8, e1 = 4096 + tid * 8;
    const int ra0 = e0 >> 5, ca0 = e0 & 31;
    const int ra1 = e1 >> 5, ca1 = e1 & 31;

#define STAGE(T, BUF)                                                         \
    {                                                                         \
        const int k0s = (T) << 5;                                             \
        gload16(Ab + k0s + (long)ra0 * lda + ca0, &ldsA[BUF][e0 & ~7]);       \
        gload16(Ab + k0s + (long)ra1 * lda + ca1, &ldsA[BUF][e1 & ~7]);       \
        gload16(Bb + k0s + (long)ra0 * ldb + ca0, &ldsB[BUF][e0 & ~7]);       \
        gload16(Bb + k0s + (long)ra1 * ldb + ca1, &ldsB[BUF][e1 & ~7]);       \
    }

    STAGE(0, 0);

    f32x4 acc[8][4] = {};
    for (int t = 0; t < nt; ++t) {
        const int buf = t & 1;
        if (t + 1 < nt) {
            STAGE(t + 1, buf ^ 1);
            asm volatile("s_waitcnt vmcnt(4)" ::: "memory");
        } else {
            asm volatile("s_waitcnt vmcnt(0)" ::: "memory");
        }
        __syncthreads();

        s16x8 af[8], bb[4];
        #pragma unroll
        for (int m = 0; m < 8; ++m)
            af[m] = *(const s16x8*)&ldsA[buf][(wr * 128 + m * 16 + fr) * 32 + kg * 8];
        #pragma unroll
        for (int nn = 0; nn < 4; ++nn)
            bb[nn] = *(const s16x8*)&ldsB[buf][(wcn * 64 + nn * 16 + fr) * 32 + kg * 8];
        #pragma unroll
        for (int m = 0; m < 8; ++m)
            #pragma unroll
            for (int nn = 0; nn < 4; ++nn)
                acc[m][nn] = __builtin_amdgcn_mfma_f32_16x16x32_bf16(af[m], bb[nn], acc[m][nn], 0, 0, 0);
        __syncthreads();
    }
#undef STAGE

    // epilogue: D mapping col=lane&15, row=(lane>>4)*4+reg
    const int cj = fr, r0q = kg * 4;
    #pragma unroll
    for (int m = 0; m < 8; ++m) {
        #pragma unroll
        for (int nn = 0; nn < 4; ++nn) {
            #pragma unroll
            for (int r = 0; r < 4; ++r) {
                const int grow = row0 + wr * 128 + m * 16 + r0q + r;
                const int gcol = col0 + wcn * 64 + nn * 16 + cj;
                float v = acc[m][nn][r];
                if constexpr (EPI == 0) {
                    // QKV scatter: q*0.125 -> [BH,T,64]; k -> [BH,T,64]; v -> vT [BH,64,T]
                    v += bias[gcol];
                    const int bbv = grow >> 10, tt = grow & 1023;
                    const int seg = gcol >> 10, mm = gcol & 1023;
                    const int hh = mm >> 6, dd = mm & 63;
                    const long bh = bbv * 16 + hh;
                    if (seg == 0)
                        outB[(bh << 16) + (tt << 6) + dd] = f2b(v * 0.125f);
                    else if (seg == 1)
                        outB[4194304 + (bh << 16) + (tt << 6) + dd] = f2b(v);
                    else
                        outB[8388608 + (bh << 16) + (dd << 10) + tt] = f2b(v);
                } else if constexpr (EPI == 4) {
                    float u = v + bias[gcol];
                    float g = 0.5f * u * (1.0f + erff(u * 0.70710678118f));
                    outB[(long)grow * ldc + gcol] = f2b(g);
                }
            }
        }
    }
}

// ---------------- 2-phase GEMM (round-8 proven) + optional XCD swizzle --------
// EPI: 1=exp(s+mask)->bf16 E + psum partials, 3=bias+resid->f32
template <int BM, int BN, int EPI, bool SWZ>
__global__ __launch_bounds__(256)
void gemm_bt(const unsigned short* __restrict__ A,
             const unsigned short* __restrict__ Bm,
             int K, int lda, int ldb, int ldc, int nx,
             long sAz, long sBz,
             const float* __restrict__ bias,
             const float* __restrict__ resid,
             float* __restrict__ outF,
             unsigned short* __restrict__ outB) {
    constexpr int WM = BM / 2, WN = BN / 2;
    constexpr int FM = WM / 16, FN = WN / 16;
    constexpr int NTA = BM / 64, NTB = BN / 64;
    constexpr int LOADS = NTA + NTB;
    __shared__ unsigned short ldsA[3][BM * 32];
    __shared__ unsigned short ldsB[3][BN * 32];

    const int tid  = threadIdx.x;
    const int lane = tid & 63;
    const int wid  = tid >> 6;
    const int wr   = wid >> 1, wc = wid & 1;
    const int bz   = blockIdx.z;

    int bx, by;
    if constexpr (SWZ) {
        const int nwg = gridDim.x, q = nwg >> 3, n = blockIdx.x;
        const int m0 = (n & 7) * q + (n >> 3);
        bx = m0 % nx; by = m0 / nx;
    } else {
        bx = blockIdx.x; by = blockIdx.y;
    }
    const int row0 = bx * BM;
    const int col0 = by * BN;

    const unsigned short* Ab = A + (long)bz * sAz + (long)row0 * lda;
    const unsigned short* Bb = Bm + (long)bz * sBz + (long)col0 * ldb;

    const int nt = K >> 5;
    f32x4 acc[FM][FN] = {};
    const int fr = lane & 15;
    const int fk = (lane >> 4) * 8;

#define STAGE(T, BUF)                                                              \
    {                                                                              \
        const int k0s = (T) << 5;                                                  \
        _Pragma("unroll")                                                          \
        for (int i = 0; i < NTA; ++i) {                                            \
            int e = i * 2048 + wid * 512 + lane * 8;                               \
            gload16(Ab + k0s + (long)(e >> 5) * lda + (e & 31),                    \
                    &ldsA[BUF][i * 2048 + wid * 512]);                             \
        }                                                                          \
        _Pragma("unroll")                                                          \
        for (int i = 0; i < NTB; ++i) {                                            \
            int e = i * 2048 + wid * 512 + lane * 8;                               \
            gload16(Bb + k0s + (long)(e >> 5) * ldb + (e & 31),                    \
                    &ldsB[BUF][i * 2048 + wid * 512]);                             \
        }                                                                          \
    }

    STAGE(0, 0);
    if (nt > 1) STAGE(1, 1);

    for (int t = 0; t < nt; ++t) {
        const int buf = t % 3;
        if (t + 1 < nt) {
            if constexpr (LOADS == 2)      asm volatile("s_waitcnt vmcnt(2)" ::: "memory");
            else if constexpr (LOADS == 3) asm volatile("s_waitcnt vmcnt(3)" ::: "memory");
            else                           asm volatile("s_waitcnt vmcnt(4)" ::: "memory");
        } else {
            asm volatile("s_waitcnt vmcnt(0)" ::: "memory");
        }
        __syncthreads();
        if (t + 2 < nt) STAGE(t + 2, (t + 2) % 3);

        s16x8 af[FM], bfr[FN];
        #pragma unroll
        for (int m = 0; m < FM; ++m)
            af[m] = *(const s16x8*)&ldsA[buf][(wr * WM + m * 16 + fr) * 32 + fk];
        #pragma unroll
        for (int n = 0; n < FN; ++n)
            bfr[n] = *(const s16x8*)&ldsB[buf][(wc * WN + n * 16 + fr) * 32 + fk];
        #pragma unroll
        for (int m = 0; m < FM; ++m)
            #pragma unroll
            for (int n = 0; n < FN; ++n)
                acc[m][n] = __builtin_amdgcn_mfma_f32_16x16x32_bf16(af[m], bfr[n], acc[m][n], 0, 0, 0);
    }
#undef STAGE

    const int cj = lane & 15;
    const int r0 = (lane >> 4) * 4;

    if constexpr (EPI == 1) {
        #pragma unroll
        for (int m = 0; m < FM; ++m) {
            #pragma unroll
            for (int r = 0; r < 4; ++r) {
                const int grow = row0 + wr * WM + m * 16 + r0 + r;
                float rs = 0.0f;
                #pragma unroll
                for (int n = 0; n < FN; ++n) {
                    const int gcol = col0 + wc * WN + n * 16 + cj;
                    float e = __expf(acc[m][n][r] + resid[((long)grow << 10) + gcol]);
                    rs += e;
                    outB[((long)bz << 20) + ((long)grow << 10) + gcol] = f2b(e);
                }
                rs += __shfl_xor(rs, 1); rs += __shfl_xor(rs, 2);
                rs += __shfl_xor(rs, 4); rs += __shfl_xor(rs, 8);
                if (cj == 0)
                    outF[((((long)bz << 10) + grow) << 4) + by * 2 + wc] = rs;
            }
        }
    } else {
        #pragma unroll
        for (int m = 0; m < FM; ++m) {
            #pragma unroll
            for (int n = 0; n < FN; ++n) {
                #pragma unroll
                for (int r = 0; r < 4; ++r) {
                    const int grow = row0 + wr * WM + m * 16 + r0 + r;
                    const int gcol = col0 + wc * WN + n * 16 + cj;
                    float v = acc[m][n][r];
                    const long idx = ((long)grow << 10) + gcol;
                    outF[idx] = v + bias[gcol] + resid[idx];
                }
            }
        }
    }
}

// ---------------- launch ----------------
extern "C" void kernel_launch(void* const* d_in, const int* in_sizes, int n_in,
                              void* d_out, int out_size, void* d_ws, size_t ws_size,
                              hipStream_t stream) {
    (void)in_sizes; (void)n_in; (void)out_size; (void)ws_size;
    const float* x     = (const float*)d_in[0];
    const float* mask  = (const float*)d_in[1];
    const float* ln1w  = (const float*)d_in[2];
    const float* ln1b  = (const float*)d_in[3];
    const float* wqkv  = (const float*)d_in[4];
    const float* bqkv  = (const float*)d_in[5];
    const float* wo    = (const float*)d_in[6];
    const float* bo    = (const float*)d_in[7];
    const float* ln2w  = (const float*)d_in[8];
    const float* ln2b  = (const float*)d_in[9];
    const float* wfc   = (const float*)d_in[10];
    const float* bfc   = (const float*)d_in[11];
    const float* wproj = (const float*)d_in[12];
    const float* bproj = (const float*)d_in[13];

    float* outx = (float*)d_out;                     // [4096,1024] fp32
    float* att  = (float*)d_out + 4194304;           // [64,1024,1024] fp32

    char* ws = (char*)d_ws;
    unsigned short* h_bf     = (unsigned short*)ws;  ws += (size_t)8  << 20;  // [4096,1024]
    unsigned short* wqkv_bf  = (unsigned short*)ws;  ws += (size_t)6  << 20;  // [3072,1024]
    unsigned short* wo_bf    = (unsigned short*)ws;  ws += (size_t)2  << 20;  // [1024,1024]
    unsigned short* wfc_bf   = (unsigned short*)ws;  ws += (size_t)8  << 20;  // [4096,1024]
    unsigned short* wproj_bf = (unsigned short*)ws;  ws += (size_t)8  << 20;  // [1024,4096]
    unsigned short* q_bf     = (unsigned short*)ws;  ws += (size_t)24 << 20;  // q,k,vT contiguous
    unsigned short* k_bf     = q_bf + 4194304;
    unsigned short* vT_bf    = q_bf + 8388608;
    unsigned short* e_b      = (unsigned short*)ws;  ws += (size_t)128 << 20; // [64,1024,1024] bf16 exp
    unsigned short* y_bf     = (unsigned short*)ws;  ws += (size_t)8  << 20;  // [4096,1024]
    float*          x2       = (float*)ws;           ws += (size_t)16 << 20;  // [4096,1024] f32
    unsigned short* gelu_bf  = (unsigned short*)ws;  ws += (size_t)32 << 20;  // [4096,4096]
    float*          psum     = (float*)ws;           ws += (size_t)4  << 20;  // [64,1024,16] f32
    float*          invl     = (float*)ws;           ws += (size_t)256 << 10; // [64,1024] f32

    // weights -> bf16 (single fused launch)
    cast4_kernel<<<12288, 256, 0, stream>>>(
        wqkv, 786432, wo, 262144, wfc, 1048576, wproj, 1048576,
        wqkv_bf, wo_bf, wfc_bf, wproj_bf);

    // LN1
    ln_kernel<<<4096, 256, 0, stream>>>(x, ln1w, ln1b, h_bf);

    // QKV: [4096,1024] x [3072,1024]^T -> q(scaled)/k/vT scatter  (256², nx=16)
    gemm256<0><<<192, 512, 0, stream>>>(
        h_bf, wqkv_bf, 1024, 1024, 1024, 0, 16, bqkv, q_bf);

    // scores: per (b,h): [1024,64] x [1024,64]^T -> E = exp(s+mask) bf16 + psum
    gemm_bt<128, 128, 1, false><<<dim3(8, 8, 64), 256, 0, stream>>>(
        q_bf, k_bf, 64, 64, 64, 0, 8, 65536, 65536,
        nullptr, mask, psum, e_b);

    // rowsum partials -> invl
    inv_kernel<<<256, 256, 0, stream>>>(psum, invl);

    // fused PV + att write
    pv_att<<<dim3(16, 64), 256, 0, stream>>>(e_b, vT_bf, invl, att, y_bf);

    // W_o: [4096,1024] x [1024,1024]^T + b_o + x -> x2  (swizzled: 1 B-panel/XCD)
    gemm_bt<64, 128, 3, true><<<512, 256, 0, stream>>>(
        y_bf, wo_bf, 1024, 1024, 1024, 1024, 64, 0, 0,
        bo, x, x2, nullptr);

    // LN2
    ln_kernel<<<4096, 256, 0, stream>>>(x2, ln2w, ln2b, h_bf);

    // FC + GELU: [4096,1024] x [4096,1024]^T -> gelu_bf  (256², nx=16)
    gemm256<4><<<256, 512, 0, stream>>>(
        h_bf, wfc_bf, 1024, 1024, 1024, 4096, 16, bfc, gelu_bf);

    // Proj: [4096,4096] x [1024,4096]^T + b_proj + x2 -> out  (swizzled: 1 B-panel/XCD)
    gemm_bt<64, 128, 3, true><<<512, 256, 0, stream>>>(
        gelu_bf, wproj_bf, 4096, 4096, 4096, 1024, 64, 0, 0,
        bproj, x2, outx, nullptr);
}

// Round 12
// 423.910 us; speedup vs baseline: 1.1526x; 1.1526x over previous
//
#include <hip/hip_runtime.h>
#include <stdint.h>
#include <math.h>

// ---------------- types ----------------
typedef __attribute__((ext_vector_type(4))) float f32x4;
typedef __attribute__((ext_vector_type(8))) short s16x8;   // 8 x bf16 (4 VGPRs)
typedef __attribute__((ext_vector_type(4))) unsigned short u16x4;

__device__ __forceinline__ unsigned short f2b(float x) {
    union { float f; uint32_t u; } v; v.f = x;
    uint32_t r = v.u + 0x7FFFu + ((v.u >> 16) & 1u);   // round-to-nearest-even
    return (unsigned short)(r >> 16);
}
__device__ __forceinline__ float b2f(unsigned short u) {
    union { uint32_t u; float f; } v; v.u = (uint32_t)u << 16;
    return v.f;
}

__device__ __forceinline__ void gload16(const unsigned short* g, unsigned short* l) {
    __builtin_amdgcn_global_load_lds(
        (const __attribute__((address_space(1))) unsigned int*)(const void*)g,
        (__attribute__((address_space(3))) unsigned int*)(void*)l,
        16, 0, 0);
}

// ---------------- fused cast(4 weights) + LN1 in one launch ----------------
__global__ __launch_bounds__(256) void castln_kernel(
        const float* __restrict__ x, const float* __restrict__ lw,
        const float* __restrict__ lb, unsigned short* __restrict__ lout,
        const float* __restrict__ a, int na, const float* __restrict__ b, int nb,
        const float* __restrict__ c, int nc, const float* __restrict__ d, int nd,
        unsigned short* __restrict__ oa, unsigned short* __restrict__ ob,
        unsigned short* __restrict__ oc, unsigned short* __restrict__ od) {
    const int tid = threadIdx.x;
    if (blockIdx.x < 4096) {
        // LayerNorm row
        const long row = blockIdx.x;
        f32x4 v = *(const f32x4*)(x + row * 1024 + tid * 4);
        float s  = v[0] + v[1] + v[2] + v[3];
        float sq = v[0]*v[0] + v[1]*v[1] + v[2]*v[2] + v[3]*v[3];
        #pragma unroll
        for (int off = 32; off; off >>= 1) {
            s  += __shfl_xor(s, off);
            sq += __shfl_xor(sq, off);
        }
        __shared__ float red[8];
        if ((tid & 63) == 0) { red[tid >> 6] = s; red[4 + (tid >> 6)] = sq; }
        __syncthreads();
        s  = red[0] + red[1] + red[2] + red[3];
        sq = red[4] + red[5] + red[6] + red[7];
        float mu  = s * (1.0f / 1024.0f);
        float var = sq * (1.0f / 1024.0f) - mu * mu;
        float rs  = rsqrtf(var + 1e-5f);
        f32x4 wv = *(const f32x4*)(lw + tid * 4);
        f32x4 bv = *(const f32x4*)(lb + tid * 4);
        u16x4 o;
        #pragma unroll
        for (int j = 0; j < 4; ++j) o[j] = f2b((v[j] - mu) * rs * wv[j] + bv[j]);
        *(u16x4*)(lout + row * 1024 + tid * 4) = o;
    } else {
        int i = (blockIdx.x - 4096) * 256 + tid;
        const float* src; unsigned short* dst; int off;
        if (i < na)                { src = a; dst = oa; off = i; }
        else if (i < na+nb)        { src = b; dst = ob; off = i - na; }
        else if (i < na+nb+nc)     { src = c; dst = oc; off = i - na - nb; }
        else if (i < na+nb+nc+nd)  { src = d; dst = od; off = i - na - nb - nc; }
        else return;
        f32x4 v = ((const f32x4*)src)[off];
        u16x4 o;
        #pragma unroll
        for (int j = 0; j < 4; ++j) o[j] = f2b(v[j]);
        ((u16x4*)dst)[off] = o;
    }
}

// ---------------- LayerNorm (standalone, LN2) ----------------
__global__ __launch_bounds__(256) void ln_kernel(const float* __restrict__ x,
                                                 const float* __restrict__ w,
                                                 const float* __restrict__ b,
                                                 unsigned short* __restrict__ out) {
    const long row = blockIdx.x;
    const int tid = threadIdx.x;
    f32x4 v = *(const f32x4*)(x + row * 1024 + tid * 4);
    float s  = v[0] + v[1] + v[2] + v[3];
    float sq = v[0]*v[0] + v[1]*v[1] + v[2]*v[2] + v[3]*v[3];
    #pragma unroll
    for (int off = 32; off; off >>= 1) {
        s  += __shfl_xor(s, off);
        sq += __shfl_xor(sq, off);
    }
    __shared__ float red[8];
    if ((tid & 63) == 0) { red[tid >> 6] = s; red[4 + (tid >> 6)] = sq; }
    __syncthreads();
    s  = red[0] + red[1] + red[2] + red[3];
    sq = red[4] + red[5] + red[6] + red[7];
    float mu  = s * (1.0f / 1024.0f);
    float var = sq * (1.0f / 1024.0f) - mu * mu;
    float rs  = rsqrtf(var + 1e-5f);
    f32x4 wv = *(const f32x4*)(w + tid * 4);
    f32x4 bv = *(const f32x4*)(b + tid * 4);
    u16x4 o;
    #pragma unroll
    for (int j = 0; j < 4; ++j) o[j] = f2b((v[j] - mu) * rs * wv[j] + bv[j]);
    *(u16x4*)(out + row * 1024 + tid * 4) = o;
}

// ---------------- fused PV + att-write + invl (psum-direct) ----------------
__global__ __launch_bounds__(256)
void pv_att(const unsigned short* __restrict__ E,    // [64][1024][1024] bf16 exp
            const unsigned short* __restrict__ Vt,   // [64][64][1024] bf16 (d-major)
            const float* __restrict__ psum,          // [64][1024][16] partials
            float* __restrict__ att,                 // [64][1024][1024] fp32
            unsigned short* __restrict__ y) {        // [4096][1024] bf16 scatter
    __shared__ unsigned short ldsA[3][64 * 32];
    __shared__ unsigned short ldsB[3][64 * 32];
    __shared__ float invl_s[64];
    const int tid = threadIdx.x, lane = tid & 63, wid = tid >> 6;
    const int wr = wid >> 1, wc = wid & 1;
    const int bh = blockIdx.y;
    const int q0 = blockIdx.x * 64;
    const int fr = lane & 15, fs = lane >> 4;

    const unsigned short* Ab = E + ((long)bh << 20) + (long)q0 * 1024;
    const unsigned short* Bb = Vt + ((long)bh << 16);

    const int e0  = wid * 512 + lane * 8;
    const int r0a = e0 >> 5, c0a = e0 & 31;
    float* attRow = att + ((long)bh << 20) + (long)(q0 + r0a) * 1024 + c0a;

    f32x4 acc[2][2] = {};

#define PSTAGE(T, BUF)                                                        \
    {                                                                         \
        const int k0s = (T) << 5;                                             \
        gload16(Ab + k0s + (long)r0a * 1024 + c0a, &ldsA[BUF][wid * 512]);    \
        gload16(Bb + k0s + (long)r0a * 1024 + c0a, &ldsB[BUF][wid * 512]);    \
    }

    PSTAGE(0, 0);
    PSTAGE(1, 1);

    // per-block invl (replaces inv_kernel): threads 0..63 sum 16 partials
    if (tid < 64) {
        const float* p = psum + ((((long)bh << 10) + q0 + tid) << 4);
        f32x4 pa = *(const f32x4*)p,       pb = *(const f32x4*)(p + 4);
        f32x4 pc = *(const f32x4*)(p + 8), pd = *(const f32x4*)(p + 12);
        float s = (pa[0]+pa[1]+pa[2]+pa[3]) + (pb[0]+pb[1]+pb[2]+pb[3])
                + (pc[0]+pc[1]+pc[2]+pc[3]) + (pd[0]+pd[1]+pd[2]+pd[3]);
        invl_s[tid] = 1.0f / s;
    }

    for (int t = 0; t < 32; ++t) {
        const int buf = t % 3;
        // ledger: outstanding = tiles t, t+1 (2 loads each); tile t landed <=> vmcnt(2)
        if (t < 31) asm volatile("s_waitcnt vmcnt(2)" ::: "memory");
        else        asm volatile("s_waitcnt vmcnt(0)" ::: "memory");
        __syncthreads();
        if (t + 2 < 32) PSTAGE(t + 2, (t + 2) % 3);

        // att write from staged tile (own 8 elems)
        {
            const float il_a = invl_s[r0a];
            s16x8 ea = *(const s16x8*)&ldsA[buf][e0];
            f32x4 o0, o1;
            #pragma unroll
            for (int j = 0; j < 4; ++j) o0[j] = b2f((unsigned short)ea[j]) * il_a;
            #pragma unroll
            for (int j = 0; j < 4; ++j) o1[j] = b2f((unsigned short)ea[4 + j]) * il_a;
            *(f32x4*)(attRow + t * 32)     = o0;
            *(f32x4*)(attRow + t * 32 + 4) = o1;
        }

        s16x8 af[2], vb[2];
        #pragma unroll
        for (int m = 0; m < 2; ++m)
            af[m] = *(const s16x8*)&ldsA[buf][(wr * 32 + m * 16 + fr) * 32 + fs * 8];
        #pragma unroll
        for (int n = 0; n < 2; ++n)
            vb[n] = *(const s16x8*)&ldsB[buf][(wc * 32 + n * 16 + fr) * 32 + fs * 8];
        #pragma unroll
        for (int m = 0; m < 2; ++m)
            #pragma unroll
            for (int n = 0; n < 2; ++n)
                acc[m][n] = __builtin_amdgcn_mfma_f32_16x16x32_bf16(af[m], vb[n], acc[m][n], 0, 0, 0);
    }
#undef PSTAGE

    // y scatter: [B,T,C] bf16, scaled by invl of the output row
    const int bb = bh >> 4, hh = bh & 15;
    #pragma unroll
    for (int m = 0; m < 2; ++m) {
        #pragma unroll
        for (int r = 0; r < 4; ++r) {
            const int lrow = wr * 32 + m * 16 + fs * 4 + r;
            const float il = invl_s[lrow];
            const int trow = q0 + lrow;
            #pragma unroll
            for (int n = 0; n < 2; ++n) {
                const int c = hh * 64 + wc * 32 + n * 16 + fr;
                y[((long)(bb * 1024 + trow) << 10) + c] = f2b(acc[m][n][r] * il);
            }
        }
    }
}

// ---------------- 2-phase GEMM (R8-proven) with coalesced bf16 epilogues --------
// EPI: 0=QKV scatter (LDS repack, v transposed), 1=exp(s+mask)->bf16 E + psum (repack),
//      3=bias+resid->f32, 4=bias+GELU->bf16 (repack)
// repack row stride = 136 (>=128, +8 pad)  [R11 bug: was 72 -> row overlap]
template <int BM, int BN, int EPI>
__global__ __launch_bounds__(256)
void gemm_bt(const unsigned short* __restrict__ A,
             const unsigned short* __restrict__ Bm,
             int K, int lda, int ldb, int ldc,
             long sAz, long sBz,
             const float* __restrict__ bias,
             const float* __restrict__ resid,
             float* __restrict__ outF,
             unsigned short* __restrict__ outB) {
    constexpr int WM = BM / 2, WN = BN / 2;
    constexpr int FM = WM / 16, FN = WN / 16;
    constexpr int NTA = BM / 64, NTB = BN / 64;
    constexpr int LOADS = NTA + NTB;
    constexpr int STR = 136;                       // repack row stride
    __shared__ unsigned short shm[3 * BM * 32 + 3 * BN * 32];
    unsigned short* ldsA = shm;
    unsigned short* ldsB = shm + 3 * BM * 32;

    const int tid  = threadIdx.x;
    const int lane = tid & 63;
    const int wid  = tid >> 6;
    const int wr   = wid >> 1, wc = wid & 1;
    const int bz   = blockIdx.z;
    const int row0 = blockIdx.x * BM;
    const int col0 = blockIdx.y * BN;

    const unsigned short* Ab = A + (long)bz * sAz + (long)row0 * lda;
    const unsigned short* Bb = Bm + (long)bz * sBz + (long)col0 * ldb;

    const int nt = K >> 5;
    f32x4 acc[FM][FN] = {};
    const int fr = lane & 15;
    const int fk = (lane >> 4) * 8;

#define STAGE(T, BUF)                                                              \
    {                                                                              \
        const int k0s = (T) << 5;                                                  \
        _Pragma("unroll")                                                          \
        for (int i = 0; i < NTA; ++i) {                                            \
            int e = i * 2048 + wid * 512 + lane * 8;                               \
            gload16(Ab + k0s + (long)(e >> 5) * lda + (e & 31),                    \
                    &ldsA[(BUF) * BM * 32 + i * 2048 + wid * 512]);                \
        }                                                                          \
        _Pragma("unroll")                                                          \
        for (int i = 0; i < NTB; ++i) {                                            \
            int e = i * 2048 + wid * 512 + lane * 8;                               \
            gload16(Bb + k0s + (long)(e >> 5) * ldb + (e & 31),                    \
                    &ldsB[(BUF) * BN * 32 + i * 2048 + wid * 512]);                \
        }                                                                          \
    }

    STAGE(0, 0);
    if (nt > 1) STAGE(1, 1);

    for (int t = 0; t < nt; ++t) {
        const int buf = t % 3;
        if (t + 1 < nt) {
            if constexpr (LOADS == 2)      asm volatile("s_waitcnt vmcnt(2)" ::: "memory");
            else if constexpr (LOADS == 3) asm volatile("s_waitcnt vmcnt(3)" ::: "memory");
            else                           asm volatile("s_waitcnt vmcnt(4)" ::: "memory");
        } else {
            asm volatile("s_waitcnt vmcnt(0)" ::: "memory");
        }
        __syncthreads();
        if (t + 2 < nt) STAGE(t + 2, (t + 2) % 3);

        s16x8 af[FM], bfr[FN];
        #pragma unroll
        for (int m = 0; m < FM; ++m)
            af[m] = *(const s16x8*)&ldsA[buf * BM * 32 + (wr * WM + m * 16 + fr) * 32 + fk];
        #pragma unroll
        for (int n = 0; n < FN; ++n)
            bfr[n] = *(const s16x8*)&ldsB[buf * BN * 32 + (wc * WN + n * 16 + fr) * 32 + fk];
        #pragma unroll
        for (int m = 0; m < FM; ++m)
            #pragma unroll
            for (int n = 0; n < FN; ++n)
                acc[m][n] = __builtin_amdgcn_mfma_f32_16x16x32_bf16(af[m], bfr[n], acc[m][n], 0, 0, 0);
    }
#undef STAGE

    // epilogue: D mapping col=lane&15, row=(lane>>4)*4+reg  [m89-verified]
    const int cj = lane & 15;
    const int r0 = (lane >> 4) * 4;

    if constexpr (EPI == 1) {
        // exp(s+mask) -> LDS repack + psum partials
        __syncthreads();                       // all LDS reads of K-loop complete
        #pragma unroll
        for (int m = 0; m < FM; ++m) {
            #pragma unroll
            for (int r = 0; r < 4; ++r) {
                const int prow = wr * WM + m * 16 + r0 + r;
                const int grow = row0 + prow;
                float rs = 0.0f;
                #pragma unroll
                for (int n = 0; n < FN; ++n) {
                    const int pcol = wc * WN + n * 16 + cj;
                    float e = __expf(acc[m][n][r] + resid[((long)grow << 10) + col0 + pcol]);
                    rs += e;
                    shm[prow * STR + pcol] = f2b(e);
                }
                rs += __shfl_xor(rs, 1); rs += __shfl_xor(rs, 2);
                rs += __shfl_xor(rs, 4); rs += __shfl_xor(rs, 8);
                if (cj == 0)
                    outF[((((long)bz << 10) + grow) << 4) + blockIdx.y * 2 + wc] = rs;
            }
        }
        __syncthreads();
        #pragma unroll
        for (int j = 0; j < 8; ++j) {
            const int idx = j * 2048 + tid * 8;
            const int row = idx >> 7, c = idx & 127;
            s16x8 val = *(const s16x8*)&shm[row * STR + c];
            *(s16x8*)(outB + ((long)bz << 20) + ((long)(row0 + row) << 10) + col0 + c) = val;
        }
    } else if constexpr (EPI == 0) {
        // QKV scatter via repack: q*0.125 -> [BH,T,64]; k -> [BH,T,64]; v -> vT [BH,64,T]
        const int seg = col0 >> 10;            // block entirely in one segment
        const int bb = row0 >> 10;
        __syncthreads();
        if (seg < 2) {
            #pragma unroll
            for (int m = 0; m < FM; ++m)
                #pragma unroll
                for (int n = 0; n < FN; ++n)
                    #pragma unroll
                    for (int r = 0; r < 4; ++r) {
                        const int prow = wr * WM + m * 16 + r0 + r;
                        const int pcol = wc * WN + n * 16 + cj;
                        float v = acc[m][n][r] + bias[col0 + pcol];
                        if (seg == 0) v *= 0.125f;
                        shm[prow * STR + pcol] = f2b(v);
                    }
            __syncthreads();
            #pragma unroll
            for (int j = 0; j < 8; ++j) {
                const int idx = j * 2048 + tid * 8;
                const int row = idx >> 7, c = idx & 127;
                s16x8 val = *(const s16x8*)&shm[row * STR + c];
                const int t = (row0 + row) & 1023;
                const int hh = ((col0 & 1023) >> 6) + (c >> 6);
                const int dd = c & 63;
                const long bh = bb * 16 + hh;
                *(s16x8*)(outB + (seg == 1 ? 4194304 : 0) + (bh << 16) + (t << 6) + dd) = val;
            }
        } else {
            // v: transpose in LDS (stride 144), flush along t
            #pragma unroll
            for (int m = 0; m < FM; ++m)
                #pragma unroll
                for (int n = 0; n < FN; ++n)
                    #pragma unroll
                    for (int r = 0; r < 4; ++r) {
                        const int prow = wr * WM + m * 16 + r0 + r;
                        const int pcol = wc * WN + n * 16 + cj;
                        shm[pcol * 144 + prow] = f2b(acc[m][n][r] + bias[col0 + pcol]);
                    }
            __syncthreads();
            #pragma unroll
            for (int j = 0; j < 8; ++j) {
                const int idx = j * 2048 + tid * 8;
                const int ddl = idx >> 7, tl = idx & 127;
                s16x8 val = *(const s16x8*)&shm[ddl * 144 + tl];
                const int hh = ((col0 & 1023) >> 6) + (ddl >> 6);
                const int dd = ddl & 63;
                const int t = (row0 & 1023) + tl;
                const long bh = bb * 16 + hh;
                *(s16x8*)(outB + 8388608 + (bh << 16) + (dd << 10) + t) = val;
            }
        }
    } else if constexpr (EPI == 4) {
        // bias + GELU -> bf16 via repack
        __syncthreads();
        #pragma unroll
        for (int m = 0; m < FM; ++m)
            #pragma unroll
            for (int n = 0; n < FN; ++n)
                #pragma unroll
                for (int r = 0; r < 4; ++r) {
                    const int prow = wr * WM + m * 16 + r0 + r;
                    const int pcol = wc * WN + n * 16 + cj;
                    float u = acc[m][n][r] + bias[col0 + pcol];
                    float g = 0.5f * u * (1.0f + erff(u * 0.70710678118f));
                    shm[prow * STR + pcol] = f2b(g);
                }
        __syncthreads();
        #pragma unroll
        for (int j = 0; j < 8; ++j) {
            const int idx = j * 2048 + tid * 8;
            const int row = idx >> 7, c = idx & 127;
            s16x8 val = *(const s16x8*)&shm[row * STR + c];
            *(s16x8*)(outB + (long)(row0 + row) * ldc + col0 + c) = val;
        }
    } else {
        // EPI 3: bias + residual -> fp32 (64B-segment stores, left as-is)
        #pragma unroll
        for (int m = 0; m < FM; ++m) {
            #pragma unroll
            for (int n = 0; n < FN; ++n) {
                #pragma unroll
                for (int r = 0; r < 4; ++r) {
                    const int grow = row0 + wr * WM + m * 16 + r0 + r;
                    const int gcol = col0 + wc * WN + n * 16 + cj;
                    const long idx = ((long)grow << 10) + gcol;
                    outF[idx] = acc[m][n][r] + bias[gcol] + resid[idx];
                }
            }
        }
    }
}

// ---------------- launch ----------------
extern "C" void kernel_launch(void* const* d_in, const int* in_sizes, int n_in,
                              void* d_out, int out_size, void* d_ws, size_t ws_size,
                              hipStream_t stream) {
    (void)in_sizes; (void)n_in; (void)out_size; (void)ws_size;
    const float* x     = (const float*)d_in[0];
    const float* mask  = (const float*)d_in[1];
    const float* ln1w  = (const float*)d_in[2];
    const float* ln1b  = (const float*)d_in[3];
    const float* wqkv  = (const float*)d_in[4];
    const float* bqkv  = (const float*)d_in[5];
    const float* wo    = (const float*)d_in[6];
    const float* bo    = (const float*)d_in[7];
    const float* ln2w  = (const float*)d_in[8];
    const float* ln2b  = (const float*)d_in[9];
    const float* wfc   = (const float*)d_in[10];
    const float* bfc   = (const float*)d_in[11];
    const float* wproj = (const float*)d_in[12];
    const float* bproj = (const float*)d_in[13];

    float* outx = (float*)d_out;                     // [4096,1024] fp32
    float* att  = (float*)d_out + 4194304;           // [64,1024,1024] fp32

    char* ws = (char*)d_ws;
    unsigned short* h_bf     = (unsigned short*)ws;  ws += (size_t)8  << 20;  // [4096,1024]
    unsigned short* wqkv_bf  = (unsigned short*)ws;  ws += (size_t)6  << 20;  // [3072,1024]
    unsigned short* wo_bf    = (unsigned short*)ws;  ws += (size_t)2  << 20;  // [1024,1024]
    unsigned short* wfc_bf   = (unsigned short*)ws;  ws += (size_t)8  << 20;  // [4096,1024]
    unsigned short* wproj_bf = (unsigned short*)ws;  ws += (size_t)8  << 20;  // [1024,4096]
    unsigned short* q_bf     = (unsigned short*)ws;  ws += (size_t)24 << 20;  // q,k,vT contiguous
    unsigned short* k_bf     = q_bf + 4194304;
    unsigned short* vT_bf    = q_bf + 8388608;
    unsigned short* e_b      = (unsigned short*)ws;  ws += (size_t)128 << 20; // [64,1024,1024] bf16 exp
    unsigned short* y_bf     = (unsigned short*)ws;  ws += (size_t)8  << 20;  // [4096,1024]
    float*          x2       = (float*)ws;           ws += (size_t)16 << 20;  // [4096,1024] f32
    unsigned short* gelu_bf  = (unsigned short*)ws;  ws += (size_t)32 << 20;  // [4096,4096]
    float*          psum     = (float*)ws;           ws += (size_t)4  << 20;  // [64,1024,16] f32

    // cast weights + LN1 in one launch
    castln_kernel<<<16384, 256, 0, stream>>>(
        x, ln1w, ln1b, h_bf,
        wqkv, 786432, wo, 262144, wfc, 1048576, wproj, 1048576,
        wqkv_bf, wo_bf, wfc_bf, wproj_bf);

    // QKV: [4096,1024] x [3072,1024]^T -> q(scaled)/k/vT scatter (repacked stores)
    gemm_bt<128, 128, 0><<<dim3(32, 24, 1), 256, 0, stream>>>(
        h_bf, wqkv_bf, 1024, 1024, 1024, 0, 0, 0,
        bqkv, nullptr, nullptr, q_bf);

    // scores: per (b,h): [1024,64] x [1024,64]^T -> E = exp(s+mask) bf16 + psum
    gemm_bt<128, 128, 1><<<dim3(8, 8, 64), 256, 0, stream>>>(
        q_bf, k_bf, 64, 64, 64, 0, 65536, 65536,
        nullptr, mask, psum, e_b);

    // fused PV + att write + invl
    pv_att<<<dim3(16, 64), 256, 0, stream>>>(e_b, vT_bf, psum, att, y_bf);

    // W_o: [4096,1024] x [1024,1024]^T + b_o + x -> x2
    gemm_bt<64, 128, 3><<<dim3(64, 8, 1), 256, 0, stream>>>(
        y_bf, wo_bf, 1024, 1024, 1024, 1024, 0, 0,
        bo, x, x2, nullptr);

    // LN2
    ln_kernel<<<4096, 256, 0, stream>>>(x2, ln2w, ln2b, h_bf);

    // FC + GELU: [4096,1024] x [4096,1024]^T -> gelu_bf [4096,4096]
    gemm_bt<128, 128, 4><<<dim3(32, 32, 1), 256, 0, stream>>>(
        h_bf, wfc_bf, 1024, 1024, 1024, 4096, 0, 0,
        bfc, nullptr, nullptr, gelu_bf);

    // Proj: [4096,4096] x [1024,4096]^T + b_proj + x2 -> out
    gemm_bt<64, 128, 3><<<dim3(64, 8, 1), 256, 0, stream>>>(
        gelu_bf, wproj_bf, 4096, 4096, 4096, 1024, 0, 0,
        bproj, x2, outx, nullptr);
}

// Round 13
// 414.319 us; speedup vs baseline: 1.1792x; 1.0231x over previous
//
#include <hip/hip_runtime.h>
#include <stdint.h>
#include <math.h>

// ---------------- types ----------------
typedef __attribute__((ext_vector_type(4))) float f32x4;
typedef __attribute__((ext_vector_type(8))) short s16x8;   // 8 x bf16 (4 VGPRs)
typedef __attribute__((ext_vector_type(4))) unsigned short u16x4;

__device__ __forceinline__ unsigned short f2b(float x) {
    union { float f; uint32_t u; } v; v.f = x;
    uint32_t r = v.u + 0x7FFFu + ((v.u >> 16) & 1u);   // round-to-nearest-even
    return (unsigned short)(r >> 16);
}
__device__ __forceinline__ float b2f(unsigned short u) {
    union { uint32_t u; float f; } v; v.u = (uint32_t)u << 16;
    return v.f;
}

__device__ __forceinline__ void gload16(const unsigned short* g, unsigned short* l) {
    __builtin_amdgcn_global_load_lds(
        (const __attribute__((address_space(1))) unsigned int*)(const void*)g,
        (__attribute__((address_space(3))) unsigned int*)(void*)l,
        16, 0, 0);
}

// tanh-form GELU (max abs dev from exact erf-GELU ~3e-4; budget 0.123)
__device__ __forceinline__ float gelu_t(float u) {
    float z = 0.7978845608f * (u + 0.044715f * u * u * u);
    float ez = __expf(2.0f * z);
    float th = 1.0f - 2.0f / (ez + 1.0f);
    return 0.5f * u * (1.0f + th);
}

// ---------------- fused cast(4 weights) + LN1 in one launch ----------------
__global__ __launch_bounds__(256) void castln_kernel(
        const float* __restrict__ x, const float* __restrict__ lw,
        const float* __restrict__ lb, unsigned short* __restrict__ lout,
        const float* __restrict__ a, int na, const float* __restrict__ b, int nb,
        const float* __restrict__ c, int nc, const float* __restrict__ d, int nd,
        unsigned short* __restrict__ oa, unsigned short* __restrict__ ob,
        unsigned short* __restrict__ oc, unsigned short* __restrict__ od) {
    const int tid = threadIdx.x;
    if (blockIdx.x < 4096) {
        // LayerNorm row
        const long row = blockIdx.x;
        f32x4 v = *(const f32x4*)(x + row * 1024 + tid * 4);
        float s  = v[0] + v[1] + v[2] + v[3];
        float sq = v[0]*v[0] + v[1]*v[1] + v[2]*v[2] + v[3]*v[3];
        #pragma unroll
        for (int off = 32; off; off >>= 1) {
            s  += __shfl_xor(s, off);
            sq += __shfl_xor(sq, off);
        }
        __shared__ float red[8];
        if ((tid & 63) == 0) { red[tid >> 6] = s; red[4 + (tid >> 6)] = sq; }
        __syncthreads();
        s  = red[0] + red[1] + red[2] + red[3];
        sq = red[4] + red[5] + red[6] + red[7];
        float mu  = s * (1.0f / 1024.0f);
        float var = sq * (1.0f / 1024.0f) - mu * mu;
        float rs  = rsqrtf(var + 1e-5f);
        f32x4 wv = *(const f32x4*)(lw + tid * 4);
        f32x4 bv = *(const f32x4*)(lb + tid * 4);
        u16x4 o;
        #pragma unroll
        for (int j = 0; j < 4; ++j) o[j] = f2b((v[j] - mu) * rs * wv[j] + bv[j]);
        *(u16x4*)(lout + row * 1024 + tid * 4) = o;
    } else {
        int i = (blockIdx.x - 4096) * 256 + tid;
        const float* src; unsigned short* dst; int off;
        if (i < na)                { src = a; dst = oa; off = i; }
        else if (i < na+nb)        { src = b; dst = ob; off = i - na; }
        else if (i < na+nb+nc)     { src = c; dst = oc; off = i - na - nb; }
        else if (i < na+nb+nc+nd)  { src = d; dst = od; off = i - na - nb - nc; }
        else return;
        f32x4 v = ((const f32x4*)src)[off];
        u16x4 o;
        #pragma unroll
        for (int j = 0; j < 4; ++j) o[j] = f2b(v[j]);
        ((u16x4*)dst)[off] = o;
    }
}

// ---------------- LayerNorm (standalone, LN2) ----------------
__global__ __launch_bounds__(256) void ln_kernel(const float* __restrict__ x,
                                                 const float* __restrict__ w,
                                                 const float* __restrict__ b,
                                                 unsigned short* __restrict__ out) {
    const long row = blockIdx.x;
    const int tid = threadIdx.x;
    f32x4 v = *(const f32x4*)(x + row * 1024 + tid * 4);
    float s  = v[0] + v[1] + v[2] + v[3];
    float sq = v[0]*v[0] + v[1]*v[1] + v[2]*v[2] + v[3]*v[3];
    #pragma unroll
    for (int off = 32; off; off >>= 1) {
        s  += __shfl_xor(s, off);
        sq += __shfl_xor(sq, off);
    }
    __shared__ float red[8];
    if ((tid & 63) == 0) { red[tid >> 6] = s; red[4 + (tid >> 6)] = sq; }
    __syncthreads();
    s  = red[0] + red[1] + red[2] + red[3];
    sq = red[4] + red[5] + red[6] + red[7];
    float mu  = s * (1.0f / 1024.0f);
    float var = sq * (1.0f / 1024.0f) - mu * mu;
    float rs  = rsqrtf(var + 1e-5f);
    f32x4 wv = *(const f32x4*)(w + tid * 4);
    f32x4 bv = *(const f32x4*)(b + tid * 4);
    u16x4 o;
    #pragma unroll
    for (int j = 0; j < 4; ++j) o[j] = f2b((v[j] - mu) * rs * wv[j] + bv[j]);
    *(u16x4*)(out + row * 1024 + tid * 4) = o;
}

// ---------------- fused PV + att-write + invl (psum-direct) ----------------
// vmcnt ledger (stores COUNT): at iter-t wait the queue is
// [loads(t), stores(t-2), loads(t+1), stores(t-1)] -> need loads(t): vmcnt(6).
// t=0: [loads0,loads1] -> vmcnt(2). t=1: [l1,l2,s0] -> vmcnt(4). t=31: [l31,s29,s30] -> vmcnt(4).
__global__ __launch_bounds__(256)
void pv_att(const unsigned short* __restrict__ E,    // [64][1024][1024] bf16 exp
            const unsigned short* __restrict__ Vt,   // [64][64][1024] bf16 (d-major)
            const float* __restrict__ psum,          // [64][1024][16] partials
            float* __restrict__ att,                 // [64][1024][1024] fp32
            unsigned short* __restrict__ y) {        // [4096][1024] bf16 scatter
    __shared__ unsigned short ldsA[3][64 * 32];
    __shared__ unsigned short ldsB[3][64 * 32];
    __shared__ float invl_s[64];
    const int tid = threadIdx.x, lane = tid & 63, wid = tid >> 6;
    const int wr = wid >> 1, wc = wid & 1;
    const int bh = blockIdx.y;
    const int q0 = blockIdx.x * 64;
    const int fr = lane & 15, fs = lane >> 4;

    const unsigned short* Ab = E + ((long)bh << 20) + (long)q0 * 1024;
    const unsigned short* Bb = Vt + ((long)bh << 16);

    const int e0  = wid * 512 + lane * 8;
    const int r0a = e0 >> 5, c0a = e0 & 31;
    float* attRow = att + ((long)bh << 20) + (long)(q0 + r0a) * 1024 + c0a;

    f32x4 acc[2][2] = {};

#define PSTAGE(T, BUF)                                                        \
    {                                                                         \
        const int k0s = (T) << 5;                                             \
        gload16(Ab + k0s + (long)r0a * 1024 + c0a, &ldsA[BUF][wid * 512]);    \
        gload16(Bb + k0s + (long)r0a * 1024 + c0a, &ldsB[BUF][wid * 512]);    \
    }

    PSTAGE(0, 0);
    PSTAGE(1, 1);

    // per-block invl: threads 0..63 sum 16 partials
    if (tid < 64) {
        const float* p = psum + ((((long)bh << 10) + q0 + tid) << 4);
        f32x4 pa = *(const f32x4*)p,       pb = *(const f32x4*)(p + 4);
        f32x4 pc = *(const f32x4*)(p + 8), pd = *(const f32x4*)(p + 12);
        float s = (pa[0]+pa[1]+pa[2]+pa[3]) + (pb[0]+pb[1]+pb[2]+pb[3])
                + (pc[0]+pc[1]+pc[2]+pc[3]) + (pd[0]+pd[1]+pd[2]+pd[3]);
        invl_s[tid] = 1.0f / s;
    }

    for (int t = 0; t < 32; ++t) {
        const int buf = t % 3;
        if (t == 0)       asm volatile("s_waitcnt vmcnt(2)" ::: "memory");
        else if (t == 1)  asm volatile("s_waitcnt vmcnt(4)" ::: "memory");
        else if (t < 31)  asm volatile("s_waitcnt vmcnt(6)" ::: "memory");
        else              asm volatile("s_waitcnt vmcnt(4)" ::: "memory");
        __syncthreads();
        if (t + 2 < 32) PSTAGE(t + 2, (t + 2) % 3);

        // att write from staged tile (own 8 elems)
        {
            const float il_a = invl_s[r0a];
            s16x8 ea = *(const s16x8*)&ldsA[buf][e0];
            f32x4 o0, o1;
            #pragma unroll
            for (int j = 0; j < 4; ++j) o0[j] = b2f((unsigned short)ea[j]) * il_a;
            #pragma unroll
            for (int j = 0; j < 4; ++j) o1[j] = b2f((unsigned short)ea[4 + j]) * il_a;
            *(f32x4*)(attRow + t * 32)     = o0;
            *(f32x4*)(attRow + t * 32 + 4) = o1;
        }

        s16x8 af[2], vb[2];
        #pragma unroll
        for (int m = 0; m < 2; ++m)
            af[m] = *(const s16x8*)&ldsA[buf][(wr * 32 + m * 16 + fr) * 32 + fs * 8];
        #pragma unroll
        for (int n = 0; n < 2; ++n)
            vb[n] = *(const s16x8*)&ldsB[buf][(wc * 32 + n * 16 + fr) * 32 + fs * 8];
        #pragma unroll
        for (int m = 0; m < 2; ++m)
            #pragma unroll
            for (int n = 0; n < 2; ++n)
                acc[m][n] = __builtin_amdgcn_mfma_f32_16x16x32_bf16(af[m], vb[n], acc[m][n], 0, 0, 0);
    }
#undef PSTAGE

    // y scatter: [B,T,C] bf16, scaled by invl of the output row
    const int bb = bh >> 4, hh = bh & 15;
    #pragma unroll
    for (int m = 0; m < 2; ++m) {
        #pragma unroll
        for (int r = 0; r < 4; ++r) {
            const int lrow = wr * 32 + m * 16 + fs * 4 + r;
            const float il = invl_s[lrow];
            const int trow = q0 + lrow;
            #pragma unroll
            for (int n = 0; n < 2; ++n) {
                const int c = hh * 64 + wc * 32 + n * 16 + fr;
                y[((long)(bb * 1024 + trow) << 10) + c] = f2b(acc[m][n][r] * il);
            }
        }
    }
}

// ---------------- 2-phase GEMM with coalesced epilogues --------
// EPI: 0=QKV scatter (LDS repack, v transposed), 1=exp(s+mask)->bf16 E + psum (repack),
//      3=bias+resid->f32 (fp32 LDS repack, coalesced f32x4), 4=bias+GELU->bf16 (repack)
template <int BM, int BN, int EPI>
__global__ __launch_bounds__(256)
void gemm_bt(const unsigned short* __restrict__ A,
             const unsigned short* __restrict__ Bm,
             int K, int lda, int ldb, int ldc,
             long sAz, long sBz,
             const float* __restrict__ bias,
             const float* __restrict__ resid,
             float* __restrict__ outF,
             unsigned short* __restrict__ outB) {
    constexpr int WM = BM / 2, WN = BN / 2;
    constexpr int FM = WM / 16, FN = WN / 16;
    constexpr int NTA = BM / 64, NTB = BN / 64;
    constexpr int LOADS = NTA + NTB;
    constexpr int STR = 136;                       // bf16 repack row stride (>=128 +8)
    constexpr int STRF = 132;                      // f32 repack row stride (128 +4)
    __shared__ unsigned short shm[3 * BM * 32 + 3 * BN * 32];
    unsigned short* ldsA = shm;
    unsigned short* ldsB = shm + 3 * BM * 32;

    const int tid  = threadIdx.x;
    const int lane = tid & 63;
    const int wid  = tid >> 6;
    const int wr   = wid >> 1, wc = wid & 1;
    const int bz   = blockIdx.z;
    const int row0 = blockIdx.x * BM;
    const int col0 = blockIdx.y * BN;

    const unsigned short* Ab = A + (long)bz * sAz + (long)row0 * lda;
    const unsigned short* Bb = Bm + (long)bz * sBz + (long)col0 * ldb;

    const int nt = K >> 5;
    f32x4 acc[FM][FN] = {};
    const int fr = lane & 15;
    const int fk = (lane >> 4) * 8;

#define STAGE(T, BUF)                                                              \
    {                                                                              \
        const int k0s = (T) << 5;                                                  \
        _Pragma("unroll")                                                          \
        for (int i = 0; i < NTA; ++i) {                                            \
            int e = i * 2048 + wid * 512 + lane * 8;                               \
            gload16(Ab + k0s + (long)(e >> 5) * lda + (e & 31),                    \
                    &ldsA[(BUF) * BM * 32 + i * 2048 + wid * 512]);                \
        }                                                                          \
        _Pragma("unroll")                                                          \
        for (int i = 0; i < NTB; ++i) {                                            \
            int e = i * 2048 + wid * 512 + lane * 8;                               \
            gload16(Bb + k0s + (long)(e >> 5) * ldb + (e & 31),                    \
                    &ldsB[(BUF) * BN * 32 + i * 2048 + wid * 512]);                \
        }                                                                          \
    }

    STAGE(0, 0);
    if (nt > 1) STAGE(1, 1);

    for (int t = 0; t < nt; ++t) {
        const int buf = t % 3;
        if (t + 1 < nt) {
            if constexpr (LOADS == 2)      asm volatile("s_waitcnt vmcnt(2)" ::: "memory");
            else if constexpr (LOADS == 3) asm volatile("s_waitcnt vmcnt(3)" ::: "memory");
            else                           asm volatile("s_waitcnt vmcnt(4)" ::: "memory");
        } else {
            asm volatile("s_waitcnt vmcnt(0)" ::: "memory");
        }
        __syncthreads();
        if (t + 2 < nt) STAGE(t + 2, (t + 2) % 3);

        s16x8 af[FM], bfr[FN];
        #pragma unroll
        for (int m = 0; m < FM; ++m)
            af[m] = *(const s16x8*)&ldsA[buf * BM * 32 + (wr * WM + m * 16 + fr) * 32 + fk];
        #pragma unroll
        for (int n = 0; n < FN; ++n)
            bfr[n] = *(const s16x8*)&ldsB[buf * BN * 32 + (wc * WN + n * 16 + fr) * 32 + fk];
        #pragma unroll
        for (int m = 0; m < FM; ++m)
            #pragma unroll
            for (int n = 0; n < FN; ++n)
                acc[m][n] = __builtin_amdgcn_mfma_f32_16x16x32_bf16(af[m], bfr[n], acc[m][n], 0, 0, 0);
    }
#undef STAGE

    // epilogue: D mapping col=lane&15, row=(lane>>4)*4+reg  [m89-verified]
    const int cj = lane & 15;
    const int r0 = (lane >> 4) * 4;

    if constexpr (EPI == 1) {
        // exp(s+mask) -> LDS repack + psum partials
        __syncthreads();
        #pragma unroll
        for (int m = 0; m < FM; ++m) {
            #pragma unroll
            for (int r = 0; r < 4; ++r) {
                const int prow = wr * WM + m * 16 + r0 + r;
                const int grow = row0 + prow;
                float rs = 0.0f;
                #pragma unroll
                for (int n = 0; n < FN; ++n) {
                    const int pcol = wc * WN + n * 16 + cj;
                    float e = __expf(acc[m][n][r] + resid[((long)grow << 10) + col0 + pcol]);
                    rs += e;
                    shm[prow * STR + pcol] = f2b(e);
                }
                rs += __shfl_xor(rs, 1); rs += __shfl_xor(rs, 2);
                rs += __shfl_xor(rs, 4); rs += __shfl_xor(rs, 8);
                if (cj == 0)
                    outF[((((long)bz << 10) + grow) << 4) + blockIdx.y * 2 + wc] = rs;
            }
        }
        __syncthreads();
        #pragma unroll
        for (int j = 0; j < 8; ++j) {
            const int idx = j * 2048 + tid * 8;
            const int row = idx >> 7, c = idx & 127;
            s16x8 val = *(const s16x8*)&shm[row * STR + c];
            *(s16x8*)(outB + ((long)bz << 20) + ((long)(row0 + row) << 10) + col0 + c) = val;
        }
    } else if constexpr (EPI == 0) {
        // QKV scatter via repack: q*0.125 -> [BH,T,64]; k -> [BH,T,64]; v -> vT [BH,64,T]
        const int seg = col0 >> 10;
        const int bb = row0 >> 10;
        __syncthreads();
        if (seg < 2) {
            #pragma unroll
            for (int m = 0; m < FM; ++m)
                #pragma unroll
                for (int n = 0; n < FN; ++n)
                    #pragma unroll
                    for (int r = 0; r < 4; ++r) {
                        const int prow = wr * WM + m * 16 + r0 + r;
                        const int pcol = wc * WN + n * 16 + cj;
                        float v = acc[m][n][r] + bias[col0 + pcol];
                        if (seg == 0) v *= 0.125f;
                        shm[prow * STR + pcol] = f2b(v);
                    }
            __syncthreads();
            #pragma unroll
            for (int j = 0; j < 8; ++j) {
                const int idx = j * 2048 + tid * 8;
                const int row = idx >> 7, c = idx & 127;
                s16x8 val = *(const s16x8*)&shm[row * STR + c];
                const int t = (row0 + row) & 1023;
                const int hh = ((col0 & 1023) >> 6) + (c >> 6);
                const int dd = c & 63;
                const long bh = bb * 16 + hh;
                *(s16x8*)(outB + (seg == 1 ? 4194304 : 0) + (bh << 16) + (t << 6) + dd) = val;
            }
        } else {
            // v: transpose in LDS (stride 144), flush along t
            #pragma unroll
            for (int m = 0; m < FM; ++m)
                #pragma unroll
                for (int n = 0; n < FN; ++n)
                    #pragma unroll
                    for (int r = 0; r < 4; ++r) {
                        const int prow = wr * WM + m * 16 + r0 + r;
                        const int pcol = wc * WN + n * 16 + cj;
                        shm[pcol * 144 + prow] = f2b(acc[m][n][r] + bias[col0 + pcol]);
                    }
            __syncthreads();
            #pragma unroll
            for (int j = 0; j < 8; ++j) {
                const int idx = j * 2048 + tid * 8;
                const int ddl = idx >> 7, tl = idx & 127;
                s16x8 val = *(const s16x8*)&shm[ddl * 144 + tl];
                const int hh = ((col0 & 1023) >> 6) + (ddl >> 6);
                const int dd = ddl & 63;
                const int t = (row0 & 1023) + tl;
                const long bh = bb * 16 + hh;
                *(s16x8*)(outB + 8388608 + (bh << 16) + (dd << 10) + t) = val;
            }
        }
    } else if constexpr (EPI == 4) {
        // bias + GELU(tanh form) -> bf16 via repack
        __syncthreads();
        #pragma unroll
        for (int m = 0; m < FM; ++m)
            #pragma unroll
            for (int n = 0; n < FN; ++n)
                #pragma unroll
                for (int r = 0; r < 4; ++r) {
                    const int prow = wr * WM + m * 16 + r0 + r;
                    const int pcol = wc * WN + n * 16 + cj;
                    float u = acc[m][n][r] + bias[col0 + pcol];
                    shm[prow * STR + pcol] = f2b(gelu_t(u));
                }
        __syncthreads();
        #pragma unroll
        for (int j = 0; j < 8; ++j) {
            const int idx = j * 2048 + tid * 8;
            const int row = idx >> 7, c = idx & 127;
            s16x8 val = *(const s16x8*)&shm[row * STR + c];
            *(s16x8*)(outB + (long)(row0 + row) * ldc + col0 + c) = val;
        }
    } else {
        // EPI 3: bias + residual -> fp32, coalesced via fp32 LDS repack
        float* shf = (float*)shm;              // BM x 128 f32, stride STRF (33 KB < 36 KB)
        __syncthreads();
        #pragma unroll
        for (int m = 0; m < FM; ++m)
            #pragma unroll
            for (int n = 0; n < FN; ++n)
                #pragma unroll
                for (int r = 0; r < 4; ++r) {
                    const int prow = wr * WM + m * 16 + r0 + r;
                    const int pcol = wc * WN + n * 16 + cj;
                    shf[prow * STRF + pcol] = acc[m][n][r];
                }
        __syncthreads();
        #pragma unroll
        for (int j = 0; j < (BM * BN / 1024); ++j) {
            const int idx = j * 1024 + tid * 4;
            const int row = idx >> 7, c = idx & 127;
            f32x4 v = *(const f32x4*)&shf[row * STRF + c];
            const long gbase = ((long)(row0 + row) << 10) + col0 + c;
            f32x4 bv = *(const f32x4*)(bias + col0 + c);
            f32x4 rv = *(const f32x4*)(resid + gbase);
            #pragma unroll
            for (int q = 0; q < 4; ++q) v[q] += bv[q] + rv[q];
            *(f32x4*)(outF + gbase) = v;
        }
    }
}

// ---------------- launch ----------------
extern "C" void kernel_launch(void* const* d_in, const int* in_sizes, int n_in,
                              void* d_out, int out_size, void* d_ws, size_t ws_size,
                              hipStream_t stream) {
    (void)in_sizes; (void)n_in; (void)out_size; (void)ws_size;
    const float* x     = (const float*)d_in[0];
    const float* mask  = (const float*)d_in[1];
    const float* ln1w  = (const float*)d_in[2];
    const float* ln1b  = (const float*)d_in[3];
    const float* wqkv  = (const float*)d_in[4];
    const float* bqkv  = (const float*)d_in[5];
    const float* wo    = (const float*)d_in[6];
    const float* bo    = (const float*)d_in[7];
    const float* ln2w  = (const float*)d_in[8];
    const float* ln2b  = (const float*)d_in[9];
    const float* wfc   = (const float*)d_in[10];
    const float* bfc   = (const float*)d_in[11];
    const float* wproj = (const float*)d_in[12];
    const float* bproj = (const float*)d_in[13];

    float* outx = (float*)d_out;                     // [4096,1024] fp32
    float* att  = (float*)d_out + 4194304;           // [64,1024,1024] fp32

    char* ws = (char*)d_ws;
    unsigned short* h_bf     = (unsigned short*)ws;  ws += (size_t)8  << 20;  // [4096,1024]
    unsigned short* wqkv_bf  = (unsigned short*)ws;  ws += (size_t)6  << 20;  // [3072,1024]
    unsigned short* wo_bf    = (unsigned short*)ws;  ws += (size_t)2  << 20;  // [1024,1024]
    unsigned short* wfc_bf   = (unsigned short*)ws;  ws += (size_t)8  << 20;  // [4096,1024]
    unsigned short* wproj_bf = (unsigned short*)ws;  ws += (size_t)8  << 20;  // [1024,4096]
    unsigned short* q_bf     = (unsigned short*)ws;  ws += (size_t)24 << 20;  // q,k,vT contiguous
    unsigned short* k_bf     = q_bf + 4194304;
    unsigned short* vT_bf    = q_bf + 8388608;
    unsigned short* e_b      = (unsigned short*)ws;  ws += (size_t)128 << 20; // [64,1024,1024] bf16 exp
    unsigned short* y_bf     = (unsigned short*)ws;  ws += (size_t)8  << 20;  // [4096,1024]
    float*          x2       = (float*)ws;           ws += (size_t)16 << 20;  // [4096,1024] f32
    unsigned short* gelu_bf  = (unsigned short*)ws;  ws += (size_t)32 << 20;  // [4096,4096]
    float*          psum     = (float*)ws;           ws += (size_t)4  << 20;  // [64,1024,16] f32

    // cast weights + LN1 in one launch
    castln_kernel<<<16384, 256, 0, stream>>>(
        x, ln1w, ln1b, h_bf,
        wqkv, 786432, wo, 262144, wfc, 1048576, wproj, 1048576,
        wqkv_bf, wo_bf, wfc_bf, wproj_bf);

    // QKV: [4096,1024] x [3072,1024]^T -> q(scaled)/k/vT scatter (repacked stores)
    gemm_bt<128, 128, 0><<<dim3(32, 24, 1), 256, 0, stream>>>(
        h_bf, wqkv_bf, 1024, 1024, 1024, 0, 0, 0,
        bqkv, nullptr, nullptr, q_bf);

    // scores: per (b,h): [1024,64] x [1024,64]^T -> E = exp(s+mask) bf16 + psum
    gemm_bt<128, 128, 1><<<dim3(8, 8, 64), 256, 0, stream>>>(
        q_bf, k_bf, 64, 64, 64, 0, 65536, 65536,
        nullptr, mask, psum, e_b);

    // fused PV + att write + invl
    pv_att<<<dim3(16, 64), 256, 0, stream>>>(e_b, vT_bf, psum, att, y_bf);

    // W_o: [4096,1024] x [1024,1024]^T + b_o + x -> x2
    gemm_bt<64, 128, 3><<<dim3(64, 8, 1), 256, 0, stream>>>(
        y_bf, wo_bf, 1024, 1024, 1024, 1024, 0, 0,
        bo, x, x2, nullptr);

    // LN2
    ln_kernel<<<4096, 256, 0, stream>>>(x2, ln2w, ln2b, h_bf);

    // FC + GELU: [4096,1024] x [4096,1024]^T -> gelu_bf [4096,4096]
    gemm_bt<128, 128, 4><<<dim3(32, 32, 1), 256, 0, stream>>>(
        h_bf, wfc_bf, 1024, 1024, 1024, 4096, 0, 0,
        bfc, nullptr, nullptr, gelu_bf);

    // Proj: [4096,4096] x [1024,4096]^T + b_proj + x2 -> out
    gemm_bt<64, 128, 3><<<dim3(64, 8, 1), 256, 0, stream>>>(
        gelu_bf, wproj_bf, 4096, 4096, 4096, 1024, 0, 0,
        bproj, x2, outx, nullptr);
}

// Round 14
// 394.499 us; speedup vs baseline: 1.2385x; 1.0502x over previous
//
#include <hip/hip_runtime.h>
#include <stdint.h>
#include <math.h>

// ---------------- types ----------------
typedef __attribute__((ext_vector_type(4))) float f32x4;
typedef __attribute__((ext_vector_type(8))) short s16x8;   // 8 x bf16 (4 VGPRs)
typedef __attribute__((ext_vector_type(4))) unsigned short u16x4;

__device__ __forceinline__ unsigned short f2b(float x) {
    union { float f; uint32_t u; } v; v.f = x;
    uint32_t r = v.u + 0x7FFFu + ((v.u >> 16) & 1u);   // round-to-nearest-even
    return (unsigned short)(r >> 16);
}
__device__ __forceinline__ float b2f(unsigned short u) {
    union { uint32_t u; float f; } v; v.u = (uint32_t)u << 16;
    return v.f;
}

__device__ __forceinline__ void gload16(const unsigned short* g, unsigned short* l) {
    __builtin_amdgcn_global_load_lds(
        (const __attribute__((address_space(1))) unsigned int*)(const void*)g,
        (__attribute__((address_space(3))) unsigned int*)(void*)l,
        16, 0, 0);
}

// tanh-form GELU (max abs dev from exact erf-GELU ~3e-4; budget 0.123)
__device__ __forceinline__ float gelu_t(float u) {
    float z = 0.7978845608f * (u + 0.044715f * u * u * u);
    float ez = __expf(2.0f * z);
    float th = 1.0f - 2.0f / (ez + 1.0f);
    return 0.5f * u * (1.0f + th);
}

// ---------------- fused cast(4 weights) + LN1 in one launch ----------------
__global__ __launch_bounds__(256) void castln_kernel(
        const float* __restrict__ x, const float* __restrict__ lw,
        const float* __restrict__ lb, unsigned short* __restrict__ lout,
        const float* __restrict__ a, int na, const float* __restrict__ b, int nb,
        const float* __restrict__ c, int nc, const float* __restrict__ d, int nd,
        unsigned short* __restrict__ oa, unsigned short* __restrict__ ob,
        unsigned short* __restrict__ oc, unsigned short* __restrict__ od) {
    const int tid = threadIdx.x;
    if (blockIdx.x < 4096) {
        const long row = blockIdx.x;
        f32x4 v = *(const f32x4*)(x + row * 1024 + tid * 4);
        float s  = v[0] + v[1] + v[2] + v[3];
        float sq = v[0]*v[0] + v[1]*v[1] + v[2]*v[2] + v[3]*v[3];
        #pragma unroll
        for (int off = 32; off; off >>= 1) {
            s  += __shfl_xor(s, off);
            sq += __shfl_xor(sq, off);
        }
        __shared__ float red[8];
        if ((tid & 63) == 0) { red[tid >> 6] = s; red[4 + (tid >> 6)] = sq; }
        __syncthreads();
        s  = red[0] + red[1] + red[2] + red[3];
        sq = red[4] + red[5] + red[6] + red[7];
        float mu  = s * (1.0f / 1024.0f);
        float var = sq * (1.0f / 1024.0f) - mu * mu;
        float rs  = rsqrtf(var + 1e-5f);
        f32x4 wv = *(const f32x4*)(lw + tid * 4);
        f32x4 bv = *(const f32x4*)(lb + tid * 4);
        u16x4 o;
        #pragma unroll
        for (int j = 0; j < 4; ++j) o[j] = f2b((v[j] - mu) * rs * wv[j] + bv[j]);
        *(u16x4*)(lout + row * 1024 + tid * 4) = o;
    } else {
        int i = (blockIdx.x - 4096) * 256 + tid;
        const float* src; unsigned short* dst; int off;
        if (i < na)                { src = a; dst = oa; off = i; }
        else if (i < na+nb)        { src = b; dst = ob; off = i - na; }
        else if (i < na+nb+nc)     { src = c; dst = oc; off = i - na - nb; }
        else if (i < na+nb+nc+nd)  { src = d; dst = od; off = i - na - nb - nc; }
        else return;
        f32x4 v = ((const f32x4*)src)[off];
        u16x4 o;
        #pragma unroll
        for (int j = 0; j < 4; ++j) o[j] = f2b(v[j]);
        ((u16x4*)dst)[off] = o;
    }
}

// ---------------- LayerNorm (standalone, LN2) ----------------
__global__ __launch_bounds__(256) void ln_kernel(const float* __restrict__ x,
                                                 const float* __restrict__ w,
                                                 const float* __restrict__ b,
                                                 unsigned short* __restrict__ out) {
    const long row = blockIdx.x;
    const int tid = threadIdx.x;
    f32x4 v = *(const f32x4*)(x + row * 1024 + tid * 4);
    float s  = v[0] + v[1] + v[2] + v[3];
    float sq = v[0]*v[0] + v[1]*v[1] + v[2]*v[2] + v[3]*v[3];
    #pragma unroll
    for (int off = 32; off; off >>= 1) {
        s  += __shfl_xor(s, off);
        sq += __shfl_xor(sq, off);
    }
    __shared__ float red[8];
    if ((tid & 63) == 0) { red[tid >> 6] = s; red[4 + (tid >> 6)] = sq; }
    __syncthreads();
    s  = red[0] + red[1] + red[2] + red[3];
    sq = red[4] + red[5] + red[6] + red[7];
    float mu  = s * (1.0f / 1024.0f);
    float var = sq * (1.0f / 1024.0f) - mu * mu;
    float rs  = rsqrtf(var + 1e-5f);
    f32x4 wv = *(const f32x4*)(w + tid * 4);
    f32x4 bv = *(const f32x4*)(b + tid * 4);
    u16x4 o;
    #pragma unroll
    for (int j = 0; j < 4; ++j) o[j] = f2b((v[j] - mu) * rs * wv[j] + bv[j]);
    *(u16x4*)(out + row * 1024 + tid * 4) = o;
}

// ---------------- fused attention pass 2: QK^T recompute + att fp32 + PV ----------------
// block: 64 q-rows x one bh, 4 waves (wave w owns q rows w*16..w*16+15).
// K/V tiles (64x64) reg-staged into padded LDS, double-buffered, 1 barrier/tile.
// P is wave-private in LDS (same-wave DS ordering -> no extra barrier).
__global__ __launch_bounds__(256)
void attn2(const unsigned short* __restrict__ Qg,   // [64][1024][64] bf16, pre-scaled
           const unsigned short* __restrict__ Kg,   // [64][1024][64] bf16
           const unsigned short* __restrict__ Vt,   // [64][64][1024] bf16 (d-major)
           const float* __restrict__ mask,          // [1024][1024] f32
           const float* __restrict__ psum,          // [64][1024][16] partials
           float* __restrict__ att,                 // [64][1024][1024] fp32 out
           unsigned short* __restrict__ y) {        // [4096][1024] bf16 scatter
    __shared__ unsigned short Ks[2][64][72];
    __shared__ unsigned short Vs[2][64][72];
    __shared__ unsigned short Ps[4][16][72];
    __shared__ float invl_s[64];
    const int tid = threadIdx.x, lane = tid & 63, wid = tid >> 6;
    const int fr = lane & 15, fs = lane >> 4;
    const int bh = blockIdx.y, q0 = blockIdx.x * 64;

    // invl per q-row (sum of 16 psum partials)
    if (tid < 64) {
        const float* p = psum + ((((long)bh << 10) + q0 + tid) << 4);
        f32x4 pa = *(const f32x4*)p,       pb = *(const f32x4*)(p + 4);
        f32x4 pc = *(const f32x4*)(p + 8), pd = *(const f32x4*)(p + 12);
        float s = (pa[0]+pa[1]+pa[2]+pa[3]) + (pb[0]+pb[1]+pb[2]+pb[3])
                + (pc[0]+pc[1]+pc[2]+pc[3]) + (pd[0]+pd[1]+pd[2]+pd[3]);
        invl_s[tid] = 1.0f / s;
    }

    // Q fragments in registers (wave-private 16 rows)
    const unsigned short* qp = Qg + ((long)bh << 16) + (long)(q0 + wid * 16 + fr) * 64 + fs * 8;
    const s16x8 aq0 = *(const s16x8*)qp;
    const s16x8 aq1 = *(const s16x8*)(qp + 32);

    // staging geometry: thread covers K/V tile row srow, 16 cols at scol
    const int srow = tid >> 2, scol = (tid & 3) * 16;
    const unsigned short* kbase = Kg + ((long)bh << 16) + (long)srow * 64 + scol;
    const unsigned short* vbase = Vt + ((long)bh << 16) + (long)srow * 1024 + scol;

    s16x8 k0a, k0b, v0a, v0b, k1a, k1b, v1a, v1b;
    k0a = *(const s16x8*)kbase;            k0b = *(const s16x8*)(kbase + 8);
    v0a = *(const s16x8*)vbase;            v0b = *(const s16x8*)(vbase + 8);
    k1a = *(const s16x8*)(kbase + 4096);   k1b = *(const s16x8*)(kbase + 4104);
    v1a = *(const s16x8*)(vbase + 64);     v1b = *(const s16x8*)(vbase + 72);

    f32x4 acc[4] = {};

#define AITER(KT, BUF, KA, KB, VA, VB)                                              \
    {                                                                               \
        *(s16x8*)&Ks[BUF][srow][scol]     = KA;                                     \
        *(s16x8*)&Ks[BUF][srow][scol + 8] = KB;                                     \
        *(s16x8*)&Vs[BUF][srow][scol]     = VA;                                     \
        *(s16x8*)&Vs[BUF][srow][scol + 8] = VB;                                     \
        __syncthreads();                                                            \
        if ((KT) + 2 < 16) {                                                        \
            const unsigned short* kp = kbase + (long)((KT) + 2) * 4096;             \
            const unsigned short* vp = vbase + ((KT) + 2) * 64;                     \
            KA = *(const s16x8*)kp;  KB = *(const s16x8*)(kp + 8);                  \
            VA = *(const s16x8*)vp;  VB = *(const s16x8*)(vp + 8);                  \
        }                                                                           \
        f32x4 s4[4];                                                                \
        _Pragma("unroll")                                                           \
        for (int n = 0; n < 4; ++n) {                                               \
            s16x8 b0 = *(const s16x8*)&Ks[BUF][n * 16 + fr][fs * 8];                \
            s16x8 b1 = *(const s16x8*)&Ks[BUF][n * 16 + fr][32 + fs * 8];           \
            f32x4 z = {};                                                           \
            z = __builtin_amdgcn_mfma_f32_16x16x32_bf16(aq0, b0, z, 0, 0, 0);       \
            z = __builtin_amdgcn_mfma_f32_16x16x32_bf16(aq1, b1, z, 0, 0, 0);       \
            s4[n] = z;                                                              \
        }                                                                           \
        _Pragma("unroll")                                                           \
        for (int r = 0; r < 4; ++r) {                                               \
            const long mb = ((long)(q0 + wid * 16 + fs * 4 + r) << 10) + (KT) * 64; \
            _Pragma("unroll")                                                       \
            for (int n = 0; n < 4; ++n) {                                           \
                float e = __expf(s4[n][r] + mask[mb + n * 16 + fr]);                \
                Ps[wid][fs * 4 + r][n * 16 + fr] = f2b(e);                          \
            }                                                                       \
        }                                                                           \
        {                                                                           \
            const float il = invl_s[srow];                                          \
            s16x8 p0 = *(const s16x8*)&Ps[wid][srow & 15][scol];                    \
            s16x8 p1 = *(const s16x8*)&Ps[wid][srow & 15][scol + 8];                \
            float* ap = att + ((long)bh << 20) + ((long)(q0 + srow) << 10)          \
                        + (KT) * 64 + scol;                                         \
            f32x4 o;                                                                \
            _Pragma("unroll") for (int j = 0; j < 4; ++j) o[j] = b2f((unsigned short)p0[j]) * il; \
            *(f32x4*)ap = o;                                                        \
            _Pragma("unroll") for (int j = 0; j < 4; ++j) o[j] = b2f((unsigned short)p0[4 + j]) * il; \
            *(f32x4*)(ap + 4) = o;                                                  \
            _Pragma("unroll") for (int j = 0; j < 4; ++j) o[j] = b2f((unsigned short)p1[j]) * il; \
            *(f32x4*)(ap + 8) = o;                                                  \
            _Pragma("unroll") for (int j = 0; j < 4; ++j) o[j] = b2f((unsigned short)p1[4 + j]) * il; \
            *(f32x4*)(ap + 12) = o;                                                 \
        }                                                                           \
        {                                                                           \
            s16x8 pa0 = *(const s16x8*)&Ps[wid][fr][fs * 8];                        \
            s16x8 pa1 = *(const s16x8*)&Ps[wid][fr][32 + fs * 8];                   \
            _Pragma("unroll")                                                       \
            for (int n = 0; n < 4; ++n) {                                           \
                s16x8 vb0 = *(const s16x8*)&Vs[BUF][n * 16 + fr][fs * 8];           \
                s16x8 vb1 = *(const s16x8*)&Vs[BUF][n * 16 + fr][32 + fs * 8];      \
                acc[n] = __builtin_amdgcn_mfma_f32_16x16x32_bf16(pa0, vb0, acc[n], 0, 0, 0); \
                acc[n] = __builtin_amdgcn_mfma_f32_16x16x32_bf16(pa1, vb1, acc[n], 0, 0, 0); \
            }                                                                       \
        }                                                                           \
    }

    for (int kt2 = 0; kt2 < 16; kt2 += 2) {
        AITER(kt2,     0, k0a, k0b, v0a, v0b);
        AITER(kt2 + 1, 1, k1a, k1b, v1a, v1b);
    }
#undef AITER

    // y scatter: [B,T,C] bf16, scaled by invl of the output row
    const int bb = bh >> 4, hh = bh & 15;
    #pragma unroll
    for (int r = 0; r < 4; ++r) {
        const int q = q0 + wid * 16 + fs * 4 + r;
        const float il = invl_s[wid * 16 + fs * 4 + r];
        #pragma unroll
        for (int n = 0; n < 4; ++n)
            y[((long)(bb * 1024 + q) << 10) + hh * 64 + n * 16 + fr] = f2b(acc[n][r] * il);
    }
}

// ---------------- 2-phase GEMM with coalesced epilogues --------
// EPI: 0=QKV scatter (LDS repack, v transposed), 3=bias+resid->f32 (fp32 repack),
//      4=bias+GELU->bf16 (repack), 5=exp(s+mask) rowsum partials ONLY (no E store)
template <int BM, int BN, int EPI>
__global__ __launch_bounds__(256)
void gemm_bt(const unsigned short* __restrict__ A,
             const unsigned short* __restrict__ Bm,
             int K, int lda, int ldb, int ldc,
             long sAz, long sBz,
             const float* __restrict__ bias,
             const float* __restrict__ resid,
             float* __restrict__ outF,
             unsigned short* __restrict__ outB) {
    constexpr int WM = BM / 2, WN = BN / 2;
    constexpr int FM = WM / 16, FN = WN / 16;
    constexpr int NTA = BM / 64, NTB = BN / 64;
    constexpr int LOADS = NTA + NTB;
    constexpr int STR = 136;                       // bf16 repack row stride
    constexpr int STRF = 132;                      // f32 repack row stride
    __shared__ unsigned short shm[3 * BM * 32 + 3 * BN * 32];
    unsigned short* ldsA = shm;
    unsigned short* ldsB = shm + 3 * BM * 32;

    const int tid  = threadIdx.x;
    const int lane = tid & 63;
    const int wid  = tid >> 6;
    const int wr   = wid >> 1, wc = wid & 1;
    const int bz   = blockIdx.z;
    const int row0 = blockIdx.x * BM;
    const int col0 = blockIdx.y * BN;

    const unsigned short* Ab = A + (long)bz * sAz + (long)row0 * lda;
    const unsigned short* Bb = Bm + (long)bz * sBz + (long)col0 * ldb;

    const int nt = K >> 5;
    f32x4 acc[FM][FN] = {};
    const int fr = lane & 15;
    const int fk = (lane >> 4) * 8;

#define STAGE(T, BUF)                                                              \
    {                                                                              \
        const int k0s = (T) << 5;                                                  \
        _Pragma("unroll")                                                          \
        for (int i = 0; i < NTA; ++i) {                                            \
            int e = i * 2048 + wid * 512 + lane * 8;                               \
            gload16(Ab + k0s + (long)(e >> 5) * lda + (e & 31),                    \
                    &ldsA[(BUF) * BM * 32 + i * 2048 + wid * 512]);                \
        }                                                                          \
        _Pragma("unroll")                                                          \
        for (int i = 0; i < NTB; ++i) {                                            \
            int e = i * 2048 + wid * 512 + lane * 8;                               \
            gload16(Bb + k0s + (long)(e >> 5) * ldb + (e & 31),                    \
                    &ldsB[(BUF) * BN * 32 + i * 2048 + wid * 512]);                \
        }                                                                          \
    }

    STAGE(0, 0);
    if (nt > 1) STAGE(1, 1);

    for (int t = 0; t < nt; ++t) {
        const int buf = t % 3;
        if (t + 1 < nt) {
            if constexpr (LOADS == 2)      asm volatile("s_waitcnt vmcnt(2)" ::: "memory");
            else if constexpr (LOADS == 3) asm volatile("s_waitcnt vmcnt(3)" ::: "memory");
            else                           asm volatile("s_waitcnt vmcnt(4)" ::: "memory");
        } else {
            asm volatile("s_waitcnt vmcnt(0)" ::: "memory");
        }
        __syncthreads();
        if (t + 2 < nt) STAGE(t + 2, (t + 2) % 3);

        s16x8 af[FM], bfr[FN];
        #pragma unroll
        for (int m = 0; m < FM; ++m)
            af[m] = *(const s16x8*)&ldsA[buf * BM * 32 + (wr * WM + m * 16 + fr) * 32 + fk];
        #pragma unroll
        for (int n = 0; n < FN; ++n)
            bfr[n] = *(const s16x8*)&ldsB[buf * BN * 32 + (wc * WN + n * 16 + fr) * 32 + fk];
        #pragma unroll
        for (int m = 0; m < FM; ++m)
            #pragma unroll
            for (int n = 0; n < FN; ++n)
                acc[m][n] = __builtin_amdgcn_mfma_f32_16x16x32_bf16(af[m], bfr[n], acc[m][n], 0, 0, 0);
    }
#undef STAGE

    // epilogue: D mapping col=lane&15, row=(lane>>4)*4+reg
    const int cj = lane & 15;
    const int r0 = (lane >> 4) * 4;

    if constexpr (EPI == 5) {
        // exp(s+mask) rowsum partials only (attn pass 1)
        #pragma unroll
        for (int m = 0; m < FM; ++m) {
            #pragma unroll
            for (int r = 0; r < 4; ++r) {
                const int grow = row0 + wr * WM + m * 16 + r0 + r;
                float rs = 0.0f;
                #pragma unroll
                for (int n = 0; n < FN; ++n) {
                    const int gcol = col0 + wc * WN + n * 16 + cj;
                    rs += __expf(acc[m][n][r] + resid[((long)grow << 10) + gcol]);
                }
                rs += __shfl_xor(rs, 1); rs += __shfl_xor(rs, 2);
                rs += __shfl_xor(rs, 4); rs += __shfl_xor(rs, 8);
                if (cj == 0)
                    outF[((((long)bz << 10) + grow) << 4) + blockIdx.y * 2 + wc] = rs;
            }
        }
    } else if constexpr (EPI == 0) {
        // QKV scatter via repack: q*0.125 -> [BH,T,64]; k -> [BH,T,64]; v -> vT [BH,64,T]
        const int seg = col0 >> 10;
        const int bb = row0 >> 10;
        __syncthreads();
        if (seg < 2) {
            #pragma unroll
            for (int m = 0; m < FM; ++m)
                #pragma unroll
                for (int n = 0; n < FN; ++n)
                    #pragma unroll
                    for (int r = 0; r < 4; ++r) {
                        const int prow = wr * WM + m * 16 + r0 + r;
                        const int pcol = wc * WN + n * 16 + cj;
                        float v = acc[m][n][r] + bias[col0 + pcol];
                        if (seg == 0) v *= 0.125f;
                        shm[prow * STR + pcol] = f2b(v);
                    }
            __syncthreads();
            #pragma unroll
            for (int j = 0; j < 8; ++j) {
                const int idx = j * 2048 + tid * 8;
                const int row = idx >> 7, c = idx & 127;
                s16x8 val = *(const s16x8*)&shm[row * STR + c];
                const int t = (row0 + row) & 1023;
                const int hh = ((col0 & 1023) >> 6) + (c >> 6);
                const int dd = c & 63;
                const long bh = bb * 16 + hh;
                *(s16x8*)(outB + (seg == 1 ? 4194304 : 0) + (bh << 16) + (t << 6) + dd) = val;
            }
        } else {
            #pragma unroll
            for (int m = 0; m < FM; ++m)
                #pragma unroll
                for (int n = 0; n < FN; ++n)
                    #pragma unroll
                    for (int r = 0; r < 4; ++r) {
                        const int prow = wr * WM + m * 16 + r0 + r;
                        const int pcol = wc * WN + n * 16 + cj;
                        shm[pcol * 144 + prow] = f2b(acc[m][n][r] + bias[col0 + pcol]);
                    }
            __syncthreads();
            #pragma unroll
            for (int j = 0; j < 8; ++j) {
                const int idx = j * 2048 + tid * 8;
                const int ddl = idx >> 7, tl = idx & 127;
                s16x8 val = *(const s16x8*)&shm[ddl * 144 + tl];
                const int hh = ((col0 & 1023) >> 6) + (ddl >> 6);
                const int dd = ddl & 63;
                const int t = (row0 & 1023) + tl;
                const long bh = bb * 16 + hh;
                *(s16x8*)(outB + 8388608 + (bh << 16) + (dd << 10) + t) = val;
            }
        }
    } else if constexpr (EPI == 4) {
        // bias + GELU(tanh form) -> bf16 via repack
        __syncthreads();
        #pragma unroll
        for (int m = 0; m < FM; ++m)
            #pragma unroll
            for (int n = 0; n < FN; ++n)
                #pragma unroll
                for (int r = 0; r < 4; ++r) {
                    const int prow = wr * WM + m * 16 + r0 + r;
                    const int pcol = wc * WN + n * 16 + cj;
                    float u = acc[m][n][r] + bias[col0 + pcol];
                    shm[prow * STR + pcol] = f2b(gelu_t(u));
                }
        __syncthreads();
        #pragma unroll
        for (int j = 0; j < 8; ++j) {
            const int idx = j * 2048 + tid * 8;
            const int row = idx >> 7, c = idx & 127;
            s16x8 val = *(const s16x8*)&shm[row * STR + c];
            *(s16x8*)(outB + (long)(row0 + row) * ldc + col0 + c) = val;
        }
    } else {
        // EPI 3: bias + residual -> fp32, coalesced via fp32 LDS repack
        float* shf = (float*)shm;
        __syncthreads();
        #pragma unroll
        for (int m = 0; m < FM; ++m)
            #pragma unroll
            for (int n = 0; n < FN; ++n)
                #pragma unroll
                for (int r = 0; r < 4; ++r) {
                    const int prow = wr * WM + m * 16 + r0 + r;
                    const int pcol = wc * WN + n * 16 + cj;
                    shf[prow * STRF + pcol] = acc[m][n][r];
                }
        __syncthreads();
        #pragma unroll
        for (int j = 0; j < (BM * BN / 1024); ++j) {
            const int idx = j * 1024 + tid * 4;
            const int row = idx >> 7, c = idx & 127;
            f32x4 v = *(const f32x4*)&shf[row * STRF + c];
            const long gbase = ((long)(row0 + row) << 10) + col0 + c;
            f32x4 bv = *(const f32x4*)(bias + col0 + c);
            f32x4 rv = *(const f32x4*)(resid + gbase);
            #pragma unroll
            for (int q = 0; q < 4; ++q) v[q] += bv[q] + rv[q];
            *(f32x4*)(outF + gbase) = v;
        }
    }
}

// ---------------- launch ----------------
extern "C" void kernel_launch(void* const* d_in, const int* in_sizes, int n_in,
                              void* d_out, int out_size, void* d_ws, size_t ws_size,
                              hipStream_t stream) {
    (void)in_sizes; (void)n_in; (void)out_size; (void)ws_size;
    const float* x     = (const float*)d_in[0];
    const float* mask  = (const float*)d_in[1];
    const float* ln1w  = (const float*)d_in[2];
    const float* ln1b  = (const float*)d_in[3];
    const float* wqkv  = (const float*)d_in[4];
    const float* bqkv  = (const float*)d_in[5];
    const float* wo    = (const float*)d_in[6];
    const float* bo    = (const float*)d_in[7];
    const float* ln2w  = (const float*)d_in[8];
    const float* ln2b  = (const float*)d_in[9];
    const float* wfc   = (const float*)d_in[10];
    const float* bfc   = (const float*)d_in[11];
    const float* wproj = (const float*)d_in[12];
    const float* bproj = (const float*)d_in[13];

    float* outx = (float*)d_out;                     // [4096,1024] fp32
    float* att  = (float*)d_out + 4194304;           // [64,1024,1024] fp32

    char* ws = (char*)d_ws;
    unsigned short* h_bf     = (unsigned short*)ws;  ws += (size_t)8  << 20;  // [4096,1024]
    unsigned short* wqkv_bf  = (unsigned short*)ws;  ws += (size_t)6  << 20;  // [3072,1024]
    unsigned short* wo_bf    = (unsigned short*)ws;  ws += (size_t)2  << 20;  // [1024,1024]
    unsigned short* wfc_bf   = (unsigned short*)ws;  ws += (size_t)8  << 20;  // [4096,1024]
    unsigned short* wproj_bf = (unsigned short*)ws;  ws += (size_t)8  << 20;  // [1024,4096]
    unsigned short* q_bf     = (unsigned short*)ws;  ws += (size_t)24 << 20;  // q,k,vT contiguous
    unsigned short* k_bf     = q_bf + 4194304;
    unsigned short* vT_bf    = q_bf + 8388608;
    unsigned short* y_bf     = (unsigned short*)ws;  ws += (size_t)8  << 20;  // [4096,1024]
    float*          x2       = (float*)ws;           ws += (size_t)16 << 20;  // [4096,1024] f32
    unsigned short* gelu_bf  = (unsigned short*)ws;  ws += (size_t)32 << 20;  // [4096,4096]
    float*          psum     = (float*)ws;           ws += (size_t)4  << 20;  // [64,1024,16] f32

    // cast weights + LN1 in one launch
    castln_kernel<<<16384, 256, 0, stream>>>(
        x, ln1w, ln1b, h_bf,
        wqkv, 786432, wo, 262144, wfc, 1048576, wproj, 1048576,
        wqkv_bf, wo_bf, wfc_bf, wproj_bf);

    // QKV: [4096,1024] x [3072,1024]^T -> q(scaled)/k/vT scatter (repacked stores)
    gemm_bt<128, 128, 0><<<dim3(32, 24, 1), 256, 0, stream>>>(
        h_bf, wqkv_bf, 1024, 1024, 1024, 0, 0, 0,
        bqkv, nullptr, nullptr, q_bf);

    // attn pass 1: per (b,h) rowsum partials only (no E store)
    gemm_bt<128, 128, 5><<<dim3(8, 8, 64), 256, 0, stream>>>(
        q_bf, k_bf, 64, 64, 64, 0, 65536, 65536,
        nullptr, mask, psum, nullptr);

    // attn pass 2: QK^T recompute + exp + att fp32 + PV -> y
    attn2<<<dim3(16, 64), 256, 0, stream>>>(
        q_bf, k_bf, vT_bf, mask, psum, att, y_bf);

    // W_o: [4096,1024] x [1024,1024]^T + b_o + x -> x2
    gemm_bt<64, 128, 3><<<dim3(64, 8, 1), 256, 0, stream>>>(
        y_bf, wo_bf, 1024, 1024, 1024, 1024, 0, 0,
        bo, x, x2, nullptr);

    // LN2
    ln_kernel<<<4096, 256, 0, stream>>>(x2, ln2w, ln2b, h_bf);

    // FC + GELU: [4096,1024] x [4096,1024]^T -> gelu_bf [4096,4096]
    gemm_bt<128, 128, 4><<<dim3(32, 32, 1), 256, 0, stream>>>(
        h_bf, wfc_bf, 1024, 1024, 1024, 4096, 0, 0,
        bfc, nullptr, nullptr, gelu_bf);

    // Proj: [4096,4096] x [1024,4096]^T + b_proj + x2 -> out
    gemm_bt<64, 128, 3><<<dim3(64, 8, 1), 256, 0, stream>>>(
        gelu_bf, wproj_bf, 4096, 4096, 4096, 1024, 0, 0,
        bproj, x2, outx, nullptr);
}

// Round 15
// 394.084 us; speedup vs baseline: 1.2398x; 1.0011x over previous
//
#include <hip/hip_runtime.h>
#include <stdint.h>
#include <math.h>

// ---------------- types ----------------
typedef __attribute__((ext_vector_type(4))) float f32x4;
typedef __attribute__((ext_vector_type(8))) short s16x8;   // 8 x bf16 (4 VGPRs)
typedef __attribute__((ext_vector_type(4))) unsigned short u16x4;

__device__ __forceinline__ unsigned short f2b(float x) {
    union { float f; uint32_t u; } v; v.f = x;
    uint32_t r = v.u + 0x7FFFu + ((v.u >> 16) & 1u);   // round-to-nearest-even
    return (unsigned short)(r >> 16);
}
__device__ __forceinline__ float b2f(unsigned short u) {
    union { uint32_t u; float f; } v; v.u = (uint32_t)u << 16;
    return v.f;
}

__device__ __forceinline__ void gload16(const unsigned short* g, unsigned short* l) {
    __builtin_amdgcn_global_load_lds(
        (const __attribute__((address_space(1))) unsigned int*)(const void*)g,
        (__attribute__((address_space(3))) unsigned int*)(void*)l,
        16, 0, 0);
}

// tanh-form GELU (max abs dev from exact erf-GELU ~3e-4; budget 0.123)
__device__ __forceinline__ float gelu_t(float u) {
    float z = 0.7978845608f * (u + 0.044715f * u * u * u);
    float ez = __expf(2.0f * z);
    float th = 1.0f - 2.0f / (ez + 1.0f);
    return 0.5f * u * (1.0f + th);
}

// ---------------- fused cast(4 weights) + LN1 in one launch ----------------
__global__ __launch_bounds__(256) void castln_kernel(
        const float* __restrict__ x, const float* __restrict__ lw,
        const float* __restrict__ lb, unsigned short* __restrict__ lout,
        const float* __restrict__ a, int na, const float* __restrict__ b, int nb,
        const float* __restrict__ c, int nc, const float* __restrict__ d, int nd,
        unsigned short* __restrict__ oa, unsigned short* __restrict__ ob,
        unsigned short* __restrict__ oc, unsigned short* __restrict__ od) {
    const int tid = threadIdx.x;
    if (blockIdx.x < 4096) {
        const long row = blockIdx.x;
        f32x4 v = *(const f32x4*)(x + row * 1024 + tid * 4);
        float s  = v[0] + v[1] + v[2] + v[3];
        float sq = v[0]*v[0] + v[1]*v[1] + v[2]*v[2] + v[3]*v[3];
        #pragma unroll
        for (int off = 32; off; off >>= 1) {
            s  += __shfl_xor(s, off);
            sq += __shfl_xor(sq, off);
        }
        __shared__ float red[8];
        if ((tid & 63) == 0) { red[tid >> 6] = s; red[4 + (tid >> 6)] = sq; }
        __syncthreads();
        s  = red[0] + red[1] + red[2] + red[3];
        sq = red[4] + red[5] + red[6] + red[7];
        float mu  = s * (1.0f / 1024.0f);
        float var = sq * (1.0f / 1024.0f) - mu * mu;
        float rs  = rsqrtf(var + 1e-5f);
        f32x4 wv = *(const f32x4*)(lw + tid * 4);
        f32x4 bv = *(const f32x4*)(lb + tid * 4);
        u16x4 o;
        #pragma unroll
        for (int j = 0; j < 4; ++j) o[j] = f2b((v[j] - mu) * rs * wv[j] + bv[j]);
        *(u16x4*)(lout + row * 1024 + tid * 4) = o;
    } else {
        int i = (blockIdx.x - 4096) * 256 + tid;
        const float* src; unsigned short* dst; int off;
        if (i < na)                { src = a; dst = oa; off = i; }
        else if (i < na+nb)        { src = b; dst = ob; off = i - na; }
        else if (i < na+nb+nc)     { src = c; dst = oc; off = i - na - nb; }
        else if (i < na+nb+nc+nd)  { src = d; dst = od; off = i - na - nb - nc; }
        else return;
        f32x4 v = ((const f32x4*)src)[off];
        u16x4 o;
        #pragma unroll
        for (int j = 0; j < 4; ++j) o[j] = f2b(v[j]);
        ((u16x4*)dst)[off] = o;
    }
}

// ---------------- LayerNorm (standalone, LN2) ----------------
__global__ __launch_bounds__(256) void ln_kernel(const float* __restrict__ x,
                                                 const float* __restrict__ w,
                                                 const float* __restrict__ b,
                                                 unsigned short* __restrict__ out) {
    const long row = blockIdx.x;
    const int tid = threadIdx.x;
    f32x4 v = *(const f32x4*)(x + row * 1024 + tid * 4);
    float s  = v[0] + v[1] + v[2] + v[3];
    float sq = v[0]*v[0] + v[1]*v[1] + v[2]*v[2] + v[3]*v[3];
    #pragma unroll
    for (int off = 32; off; off >>= 1) {
        s  += __shfl_xor(s, off);
        sq += __shfl_xor(sq, off);
    }
    __shared__ float red[8];
    if ((tid & 63) == 0) { red[tid >> 6] = s; red[4 + (tid >> 6)] = sq; }
    __syncthreads();
    s  = red[0] + red[1] + red[2] + red[3];
    sq = red[4] + red[5] + red[6] + red[7];
    float mu  = s * (1.0f / 1024.0f);
    float var = sq * (1.0f / 1024.0f) - mu * mu;
    float rs  = rsqrtf(var + 1e-5f);
    f32x4 wv = *(const f32x4*)(w + tid * 4);
    f32x4 bv = *(const f32x4*)(b + tid * 4);
    u16x4 o;
    #pragma unroll
    for (int j = 0; j < 4; ++j) o[j] = f2b((v[j] - mu) * rs * wv[j] + bv[j]);
    *(u16x4*)(out + row * 1024 + tid * 4) = o;
}

// ---------------- fused attention pass 2 (R14-proven) ----------------
__global__ __launch_bounds__(256)
void attn2(const unsigned short* __restrict__ Qg,   // [64][1024][64] bf16, pre-scaled
           const unsigned short* __restrict__ Kg,   // [64][1024][64] bf16
           const unsigned short* __restrict__ Vt,   // [64][64][1024] bf16 (d-major)
           const float* __restrict__ mask,          // [1024][1024] f32
           const float* __restrict__ psum,          // [64][1024][16] partials
           float* __restrict__ att,                 // [64][1024][1024] fp32 out
           unsigned short* __restrict__ y) {        // [4096][1024] bf16 scatter
    __shared__ unsigned short Ks[2][64][72];
    __shared__ unsigned short Vs[2][64][72];
    __shared__ unsigned short Ps[4][16][72];
    __shared__ float invl_s[64];
    const int tid = threadIdx.x, lane = tid & 63, wid = tid >> 6;
    const int fr = lane & 15, fs = lane >> 4;
    const int bh = blockIdx.y, q0 = blockIdx.x * 64;

    if (tid < 64) {
        const float* p = psum + ((((long)bh << 10) + q0 + tid) << 4);
        f32x4 pa = *(const f32x4*)p,       pb = *(const f32x4*)(p + 4);
        f32x4 pc = *(const f32x4*)(p + 8), pd = *(const f32x4*)(p + 12);
        float s = (pa[0]+pa[1]+pa[2]+pa[3]) + (pb[0]+pb[1]+pb[2]+pb[3])
                + (pc[0]+pc[1]+pc[2]+pc[3]) + (pd[0]+pd[1]+pd[2]+pd[3]);
        invl_s[tid] = 1.0f / s;
    }

    const unsigned short* qp = Qg + ((long)bh << 16) + (long)(q0 + wid * 16 + fr) * 64 + fs * 8;
    const s16x8 aq0 = *(const s16x8*)qp;
    const s16x8 aq1 = *(const s16x8*)(qp + 32);

    const int srow = tid >> 2, scol = (tid & 3) * 16;
    const unsigned short* kbase = Kg + ((long)bh << 16) + (long)srow * 64 + scol;
    const unsigned short* vbase = Vt + ((long)bh << 16) + (long)srow * 1024 + scol;

    s16x8 k0a, k0b, v0a, v0b, k1a, k1b, v1a, v1b;
    k0a = *(const s16x8*)kbase;            k0b = *(const s16x8*)(kbase + 8);
    v0a = *(const s16x8*)vbase;            v0b = *(const s16x8*)(vbase + 8);
    k1a = *(const s16x8*)(kbase + 4096);   k1b = *(const s16x8*)(kbase + 4104);
    v1a = *(const s16x8*)(vbase + 64);     v1b = *(const s16x8*)(vbase + 72);

    f32x4 acc[4] = {};

#define AITER(KT, BUF, KA, KB, VA, VB)                                              \
    {                                                                               \
        *(s16x8*)&Ks[BUF][srow][scol]     = KA;                                     \
        *(s16x8*)&Ks[BUF][srow][scol + 8] = KB;                                     \
        *(s16x8*)&Vs[BUF][srow][scol]     = VA;                                     \
        *(s16x8*)&Vs[BUF][srow][scol + 8] = VB;                                     \
        __syncthreads();                                                            \
        if ((KT) + 2 < 16) {                                                        \
            const unsigned short* kp = kbase + (long)((KT) + 2) * 4096;             \
            const unsigned short* vp = vbase + ((KT) + 2) * 64;                     \
            KA = *(const s16x8*)kp;  KB = *(const s16x8*)(kp + 8);                  \
            VA = *(const s16x8*)vp;  VB = *(const s16x8*)(vp + 8);                  \
        }                                                                           \
        f32x4 s4[4];                                                                \
        _Pragma("unroll")                                                           \
        for (int n = 0; n < 4; ++n) {                                               \
            s16x8 b0 = *(const s16x8*)&Ks[BUF][n * 16 + fr][fs * 8];                \
            s16x8 b1 = *(const s16x8*)&Ks[BUF][n * 16 + fr][32 + fs * 8];           \
            f32x4 z = {};                                                           \
            z = __builtin_amdgcn_mfma_f32_16x16x32_bf16(aq0, b0, z, 0, 0, 0);       \
            z = __builtin_amdgcn_mfma_f32_16x16x32_bf16(aq1, b1, z, 0, 0, 0);       \
            s4[n] = z;                                                              \
        }                                                                           \
        _Pragma("unroll")                                                           \
        for (int r = 0; r < 4; ++r) {                                               \
            const long mb = ((long)(q0 + wid * 16 + fs * 4 + r) << 10) + (KT) * 64; \
            _Pragma("unroll")                                                       \
            for (int n = 0; n < 4; ++n) {                                           \
                float e = __expf(s4[n][r] + mask[mb + n * 16 + fr]);                \
                Ps[wid][fs * 4 + r][n * 16 + fr] = f2b(e);                          \
            }                                                                       \
        }                                                                           \
        {                                                                           \
            const float il = invl_s[srow];                                          \
            s16x8 p0 = *(const s16x8*)&Ps[wid][srow & 15][scol];                    \
            s16x8 p1 = *(const s16x8*)&Ps[wid][srow & 15][scol + 8];                \
            float* ap = att + ((long)bh << 20) + ((long)(q0 + srow) << 10)          \
                        + (KT) * 64 + scol;                                         \
            f32x4 o;                                                                \
            _Pragma("unroll") for (int j = 0; j < 4; ++j) o[j] = b2f((unsigned short)p0[j]) * il; \
            *(f32x4*)ap = o;                                                        \
            _Pragma("unroll") for (int j = 0; j < 4; ++j) o[j] = b2f((unsigned short)p0[4 + j]) * il; \
            *(f32x4*)(ap + 4) = o;                                                  \
            _Pragma("unroll") for (int j = 0; j < 4; ++j) o[j] = b2f((unsigned short)p1[j]) * il; \
            *(f32x4*)(ap + 8) = o;                                                  \
            _Pragma("unroll") for (int j = 0; j < 4; ++j) o[j] = b2f((unsigned short)p1[4 + j]) * il; \
            *(f32x4*)(ap + 12) = o;                                                 \
        }                                                                           \
        {                                                                           \
            s16x8 pa0 = *(const s16x8*)&Ps[wid][fr][fs * 8];                        \
            s16x8 pa1 = *(const s16x8*)&Ps[wid][fr][32 + fs * 8];                   \
            _Pragma("unroll")                                                       \
            for (int n = 0; n < 4; ++n) {                                           \
                s16x8 vb0 = *(const s16x8*)&Vs[BUF][n * 16 + fr][fs * 8];           \
                s16x8 vb1 = *(const s16x8*)&Vs[BUF][n * 16 + fr][32 + fs * 8];      \
                acc[n] = __builtin_amdgcn_mfma_f32_16x16x32_bf16(pa0, vb0, acc[n], 0, 0, 0); \
                acc[n] = __builtin_amdgcn_mfma_f32_16x16x32_bf16(pa1, vb1, acc[n], 0, 0, 0); \
            }                                                                       \
        }                                                                           \
    }

    for (int kt2 = 0; kt2 < 16; kt2 += 2) {
        AITER(kt2,     0, k0a, k0b, v0a, v0b);
        AITER(kt2 + 1, 1, k1a, k1b, v1a, v1b);
    }
#undef AITER

    const int bb = bh >> 4, hh = bh & 15;
    #pragma unroll
    for (int r = 0; r < 4; ++r) {
        const int q = q0 + wid * 16 + fs * 4 + r;
        const float il = invl_s[wid * 16 + fs * 4 + r];
        #pragma unroll
        for (int n = 0; n < 4; ++n)
            y[((long)(bb * 1024 + q) << 10) + hh * 64 + n * 16 + fr] = f2b(acc[n][r] * il);
    }
}

// ---------------- 256x256 phase-interleaved GEMM (FC): T3+T4+T5, linear LDS ----------------
// 8 waves (2M x 4N), BK=32, 3 buffers (96 KB), 2 phases/K-tile:
// each phase {counted wait -> barrier -> ds_reads -> issue 2 gload_lds(t+2) -> setprio(1)
// -> 16 MFMA -> setprio(0)}. vmcnt(4) at K-tile boundary (tile t+1 in flight), never 0
// in steady state. Epilogue: GELU -> bf16 via 2-pass LDS repack, coalesced 16B stores.
__global__ __launch_bounds__(512, 2)
void gemm8p_fc(const unsigned short* __restrict__ A,    // [4096][1024] bf16
               const unsigned short* __restrict__ Bm,   // [4096][1024] bf16
               const float* __restrict__ bias,          // [4096]
               unsigned short* __restrict__ outB) {     // [4096][4096] bf16
    __shared__ unsigned short shm8[49152];               // 96 KB: A bufs [0..24575], B bufs [24576..]
    const int tid = threadIdx.x, lane = tid & 63, wid = tid >> 6;
    const int wr = wid >> 2, wcn = wid & 3;
    const int fr = lane & 15, kg = lane >> 4;
    const int row0 = blockIdx.x * 256, col0 = blockIdx.y * 256;
    const unsigned short* Ab = A + (long)row0 * 1024;
    const unsigned short* Bb = Bm + (long)col0 * 1024;

    // staging geometry: thread covers row sr (+128 for upper half), 8 elems at col sc
    const int sr = tid >> 2, sc = (tid & 3) * 8;
    // LDS dest = buf*8192 + half*4096 + wid*512 + lane*8  (wave-uniform base + lane*16B)
#define STG_A(T, H) gload16(Ab + (long)(sr + (H) * 128) * 1024 + ((T) << 5) + sc, \
                            &shm8[((T) % 3) * 8192 + (H) * 4096 + wid * 512 + lane * 8])
#define STG_B(T, H) gload16(Bb + (long)(sr + (H) * 128) * 1024 + ((T) << 5) + sc, \
                            &shm8[24576 + ((T) % 3) * 8192 + (H) * 4096 + wid * 512 + lane * 8])

    // prologue: tiles 0 and 1 (4 loads each)
    STG_A(0, 0); STG_A(0, 1); STG_B(0, 0); STG_B(0, 1);
    STG_A(1, 0); STG_A(1, 1); STG_B(1, 0); STG_B(1, 1);

    f32x4 acc[8][4] = {};

    for (int t = 0; t < 32; ++t) {
        const int buf = t % 3;
        const unsigned short* As = &shm8[buf * 8192];
        const unsigned short* Bs = &shm8[24576 + buf * 8192];
        // ledger: outstanding = tile t+1's 4 loads (t+2's issued below, after this wait)
        if (t < 31) asm volatile("s_waitcnt vmcnt(4)" ::: "memory");
        else        asm volatile("s_waitcnt vmcnt(0)" ::: "memory");
        __syncthreads();

        // ---- phase 0: B(all) + A(m0-3), stage A(t+2), MFMA m0-3 ----
        s16x8 bb[4], af[4];
        #pragma unroll
        for (int n = 0; n < 4; ++n)
            bb[n] = *(const s16x8*)&Bs[(wcn * 64 + n * 16 + fr) * 32 + kg * 8];
        #pragma unroll
        for (int m = 0; m < 4; ++m)
            af[m] = *(const s16x8*)&As[(wr * 128 + m * 16 + fr) * 32 + kg * 8];
        if (t + 2 < 32) { STG_A(t + 2, 0); STG_A(t + 2, 1); }
        __builtin_amdgcn_s_setprio(1);
        #pragma unroll
        for (int m = 0; m < 4; ++m)
            #pragma unroll
            for (int n = 0; n < 4; ++n)
                acc[m][n] = __builtin_amdgcn_mfma_f32_16x16x32_bf16(af[m], bb[n], acc[m][n], 0, 0, 0);
        __builtin_amdgcn_s_setprio(0);
        __syncthreads();

        // ---- phase 1: A(m4-7), stage B(t+2), MFMA m4-7 ----
        #pragma unroll
        for (int m = 0; m < 4; ++m)
            af[m] = *(const s16x8*)&As[(wr * 128 + (m + 4) * 16 + fr) * 32 + kg * 8];
        if (t + 2 < 32) { STG_B(t + 2, 0); STG_B(t + 2, 1); }
        __builtin_amdgcn_s_setprio(1);
        #pragma unroll
        for (int m = 0; m < 4; ++m)
            #pragma unroll
            for (int n = 0; n < 4; ++n)
                acc[m + 4][n] = __builtin_amdgcn_mfma_f32_16x16x32_bf16(af[m], bb[n], acc[m + 4][n], 0, 0, 0);
        __builtin_amdgcn_s_setprio(0);
    }
#undef STG_A
#undef STG_B

    // ---- epilogue: GELU -> bf16, 2-pass repack (rows 0-127, 128-255), stride 264 ----
    #pragma unroll
    for (int h = 0; h < 2; ++h) {
        __syncthreads();
        if (wr == h) {
            #pragma unroll
            for (int m = 0; m < 8; ++m)
                #pragma unroll
                for (int n = 0; n < 4; ++n)
                    #pragma unroll
                    for (int r = 0; r < 4; ++r) {
                        const int prow = m * 16 + kg * 4 + r;          // 0..127
                        const int pcol = wcn * 64 + n * 16 + fr;       // 0..255
                        float u = acc[m][n][r] + bias[col0 + pcol];
                        shm8[prow * 264 + pcol] = f2b(gelu_t(u));
                    }
        }
        __syncthreads();
        #pragma unroll
        for (int j = 0; j < 8; ++j) {
            const int idx = j * 4096 + tid * 8;
            const int row = idx >> 8, c = idx & 255;
            s16x8 val = *(const s16x8*)&shm8[row * 264 + c];
            *(s16x8*)(outB + (long)(row0 + h * 128 + row) * 4096 + col0 + c) = val;
        }
    }
}

// ---------------- 2-phase GEMM with coalesced epilogues (R14-proven) --------
// EPI: 0=QKV scatter, 3=bias+resid->f32, 5=exp(s+mask) rowsum partials only
template <int BM, int BN, int EPI>
__global__ __launch_bounds__(256)
void gemm_bt(const unsigned short* __restrict__ A,
             const unsigned short* __restrict__ Bm,
             int K, int lda, int ldb, int ldc,
             long sAz, long sBz,
             const float* __restrict__ bias,
             const float* __restrict__ resid,
             float* __restrict__ outF,
             unsigned short* __restrict__ outB) {
    constexpr int WM = BM / 2, WN = BN / 2;
    constexpr int FM = WM / 16, FN = WN / 16;
    constexpr int NTA = BM / 64, NTB = BN / 64;
    constexpr int LOADS = NTA + NTB;
    constexpr int STR = 136;
    constexpr int STRF = 132;
    __shared__ unsigned short shm[3 * BM * 32 + 3 * BN * 32];
    unsigned short* ldsA = shm;
    unsigned short* ldsB = shm + 3 * BM * 32;

    const int tid  = threadIdx.x;
    const int lane = tid & 63;
    const int wid  = tid >> 6;
    const int wr   = wid >> 1, wc = wid & 1;
    const int bz   = blockIdx.z;
    const int row0 = blockIdx.x * BM;
    const int col0 = blockIdx.y * BN;

    const unsigned short* Ab = A + (long)bz * sAz + (long)row0 * lda;
    const unsigned short* Bb = Bm + (long)bz * sBz + (long)col0 * ldb;

    const int nt = K >> 5;
    f32x4 acc[FM][FN] = {};
    const int fr = lane & 15;
    const int fk = (lane >> 4) * 8;

#define STAGE(T, BUF)                                                              \
    {                                                                              \
        const int k0s = (T) << 5;                                                  \
        _Pragma("unroll")                                                          \
        for (int i = 0; i < NTA; ++i) {                                            \
            int e = i * 2048 + wid * 512 + lane * 8;                               \
            gload16(Ab + k0s + (long)(e >> 5) * lda + (e & 31),                    \
                    &ldsA[(BUF) * BM * 32 + i * 2048 + wid * 512]);                \
        }                                                                          \
        _Pragma("unroll")                                                          \
        for (int i = 0; i < NTB; ++i) {                                            \
            int e = i * 2048 + wid * 512 + lane * 8;                               \
            gload16(Bb + k0s + (long)(e >> 5) * ldb + (e & 31),                    \
                    &ldsB[(BUF) * BN * 32 + i * 2048 + wid * 512]);                \
        }                                                                          \
    }

    STAGE(0, 0);
    if (nt > 1) STAGE(1, 1);

    for (int t = 0; t < nt; ++t) {
        const int buf = t % 3;
        if (t + 1 < nt) {
            if constexpr (LOADS == 2)      asm volatile("s_waitcnt vmcnt(2)" ::: "memory");
            else if constexpr (LOADS == 3) asm volatile("s_waitcnt vmcnt(3)" ::: "memory");
            else                           asm volatile("s_waitcnt vmcnt(4)" ::: "memory");
        } else {
            asm volatile("s_waitcnt vmcnt(0)" ::: "memory");
        }
        __syncthreads();
        if (t + 2 < nt) STAGE(t + 2, (t + 2) % 3);

        s16x8 af[FM], bfr[FN];
        #pragma unroll
        for (int m = 0; m < FM; ++m)
            af[m] = *(const s16x8*)&ldsA[buf * BM * 32 + (wr * WM + m * 16 + fr) * 32 + fk];
        #pragma unroll
        for (int n = 0; n < FN; ++n)
            bfr[n] = *(const s16x8*)&ldsB[buf * BN * 32 + (wc * WN + n * 16 + fr) * 32 + fk];
        #pragma unroll
        for (int m = 0; m < FM; ++m)
            #pragma unroll
            for (int n = 0; n < FN; ++n)
                acc[m][n] = __builtin_amdgcn_mfma_f32_16x16x32_bf16(af[m], bfr[n], acc[m][n], 0, 0, 0);
    }
#undef STAGE

    const int cj = lane & 15;
    const int r0 = (lane >> 4) * 4;

    if constexpr (EPI == 5) {
        #pragma unroll
        for (int m = 0; m < FM; ++m) {
            #pragma unroll
            for (int r = 0; r < 4; ++r) {
                const int grow = row0 + wr * WM + m * 16 + r0 + r;
                float rs = 0.0f;
                #pragma unroll
                for (int n = 0; n < FN; ++n) {
                    const int gcol = col0 + wc * WN + n * 16 + cj;
                    rs += __expf(acc[m][n][r] + resid[((long)grow << 10) + gcol]);
                }
                rs += __shfl_xor(rs, 1); rs += __shfl_xor(rs, 2);
                rs += __shfl_xor(rs, 4); rs += __shfl_xor(rs, 8);
                if (cj == 0)
                    outF[((((long)bz << 10) + grow) << 4) + blockIdx.y * 2 + wc] = rs;
            }
        }
    } else if constexpr (EPI == 0) {
        const int seg = col0 >> 10;
        const int bb = row0 >> 10;
        __syncthreads();
        if (seg < 2) {
            #pragma unroll
            for (int m = 0; m < FM; ++m)
                #pragma unroll
                for (int n = 0; n < FN; ++n)
                    #pragma unroll
                    for (int r = 0; r < 4; ++r) {
                        const int prow = wr * WM + m * 16 + r0 + r;
                        const int pcol = wc * WN + n * 16 + cj;
                        float v = acc[m][n][r] + bias[col0 + pcol];
                        if (seg == 0) v *= 0.125f;
                        shm[prow * STR + pcol] = f2b(v);
                    }
            __syncthreads();
            #pragma unroll
            for (int j = 0; j < 8; ++j) {
                const int idx = j * 2048 + tid * 8;
                const int row = idx >> 7, c = idx & 127;
                s16x8 val = *(const s16x8*)&shm[row * STR + c];
                const int t = (row0 + row) & 1023;
                const int hh = ((col0 & 1023) >> 6) + (c >> 6);
                const int dd = c & 63;
                const long bh = bb * 16 + hh;
                *(s16x8*)(outB + (seg == 1 ? 4194304 : 0) + (bh << 16) + (t << 6) + dd) = val;
            }
        } else {
            #pragma unroll
            for (int m = 0; m < FM; ++m)
                #pragma unroll
                for (int n = 0; n < FN; ++n)
                    #pragma unroll
                    for (int r = 0; r < 4; ++r) {
                        const int prow = wr * WM + m * 16 + r0 + r;
                        const int pcol = wc * WN + n * 16 + cj;
                        shm[pcol * 144 + prow] = f2b(acc[m][n][r] + bias[col0 + pcol]);
                    }
            __syncthreads();
            #pragma unroll
            for (int j = 0; j < 8; ++j) {
                const int idx = j * 2048 + tid * 8;
                const int ddl = idx >> 7, tl = idx & 127;
                s16x8 val = *(const s16x8*)&shm[ddl * 144 + tl];
                const int hh = ((col0 & 1023) >> 6) + (ddl >> 6);
                const int dd = ddl & 63;
                const int t = (row0 & 1023) + tl;
                const long bh = bb * 16 + hh;
                *(s16x8*)(outB + 8388608 + (bh << 16) + (dd << 10) + t) = val;
            }
        }
    } else {
        // EPI 3: bias + residual -> fp32, coalesced via fp32 LDS repack
        float* shf = (float*)shm;
        __syncthreads();
        #pragma unroll
        for (int m = 0; m < FM; ++m)
            #pragma unroll
            for (int n = 0; n < FN; ++n)
                #pragma unroll
                for (int r = 0; r < 4; ++r) {
                    const int prow = wr * WM + m * 16 + r0 + r;
                    const int pcol = wc * WN + n * 16 + cj;
                    shf[prow * STRF + pcol] = acc[m][n][r];
                }
        __syncthreads();
        #pragma unroll
        for (int j = 0; j < (BM * BN / 1024); ++j) {
            const int idx = j * 1024 + tid * 4;
            const int row = idx >> 7, c = idx & 127;
            f32x4 v = *(const f32x4*)&shf[row * STRF + c];
            const long gbase = ((long)(row0 + row) << 10) + col0 + c;
            f32x4 bv = *(const f32x4*)(bias + col0 + c);
            f32x4 rv = *(const f32x4*)(resid + gbase);
            #pragma unroll
            for (int q = 0; q < 4; ++q) v[q] += bv[q] + rv[q];
            *(f32x4*)(outF + gbase) = v;
        }
    }
}

// ---------------- launch ----------------
extern "C" void kernel_launch(void* const* d_in, const int* in_sizes, int n_in,
                              void* d_out, int out_size, void* d_ws, size_t ws_size,
                              hipStream_t stream) {
    (void)in_sizes; (void)n_in; (void)out_size; (void)ws_size;
    const float* x     = (const float*)d_in[0];
    const float* mask  = (const float*)d_in[1];
    const float* ln1w  = (const float*)d_in[2];
    const float* ln1b  = (const float*)d_in[3];
    const float* wqkv  = (const float*)d_in[4];
    const float* bqkv  = (const float*)d_in[5];
    const float* wo    = (const float*)d_in[6];
    const float* bo    = (const float*)d_in[7];
    const float* ln2w  = (const float*)d_in[8];
    const float* ln2b  = (const float*)d_in[9];
    const float* wfc   = (const float*)d_in[10];
    const float* bfc   = (const float*)d_in[11];
    const float* wproj = (const float*)d_in[12];
    const float* bproj = (const float*)d_in[13];

    float* outx = (float*)d_out;                     // [4096,1024] fp32
    float* att  = (float*)d_out + 4194304;           // [64,1024,1024] fp32

    char* ws = (char*)d_ws;
    unsigned short* h_bf     = (unsigned short*)ws;  ws += (size_t)8  << 20;  // [4096,1024]
    unsigned short* wqkv_bf  = (unsigned short*)ws;  ws += (size_t)6  << 20;  // [3072,1024]
    unsigned short* wo_bf    = (unsigned short*)ws;  ws += (size_t)2  << 20;  // [1024,1024]
    unsigned short* wfc_bf   = (unsigned short*)ws;  ws += (size_t)8  << 20;  // [4096,1024]
    unsigned short* wproj_bf = (unsigned short*)ws;  ws += (size_t)8  << 20;  // [1024,4096]
    unsigned short* q_bf     = (unsigned short*)ws;  ws += (size_t)24 << 20;  // q,k,vT contiguous
    unsigned short* k_bf     = q_bf + 4194304;
    unsigned short* vT_bf    = q_bf + 8388608;
    unsigned short* y_bf     = (unsigned short*)ws;  ws += (size_t)8  << 20;  // [4096,1024]
    float*          x2       = (float*)ws;           ws += (size_t)16 << 20;  // [4096,1024] f32
    unsigned short* gelu_bf  = (unsigned short*)ws;  ws += (size_t)32 << 20;  // [4096,4096]
    float*          psum     = (float*)ws;           ws += (size_t)4  << 20;  // [64,1024,16] f32

    // cast weights + LN1 in one launch
    castln_kernel<<<16384, 256, 0, stream>>>(
        x, ln1w, ln1b, h_bf,
        wqkv, 786432, wo, 262144, wfc, 1048576, wproj, 1048576,
        wqkv_bf, wo_bf, wfc_bf, wproj_bf);

    // QKV: [4096,1024] x [3072,1024]^T -> q(scaled)/k/vT scatter (repacked stores)
    gemm_bt<128, 128, 0><<<dim3(32, 24, 1), 256, 0, stream>>>(
        h_bf, wqkv_bf, 1024, 1024, 1024, 0, 0, 0,
        bqkv, nullptr, nullptr, q_bf);

    // attn pass 1: per (b,h) rowsum partials only (no E store)
    gemm_bt<128, 128, 5><<<dim3(8, 8, 64), 256, 0, stream>>>(
        q_bf, k_bf, 64, 64, 64, 0, 65536, 65536,
        nullptr, mask, psum, nullptr);

    // attn pass 2: QK^T recompute + exp + att fp32 + PV -> y
    attn2<<<dim3(16, 64), 256, 0, stream>>>(
        q_bf, k_bf, vT_bf, mask, psum, att, y_bf);

    // W_o: [4096,1024] x [1024,1024]^T + b_o + x -> x2
    gemm_bt<64, 128, 3><<<dim3(64, 8, 1), 256, 0, stream>>>(
        y_bf, wo_bf, 1024, 1024, 1024, 1024, 0, 0,
        bo, x, x2, nullptr);

    // LN2
    ln_kernel<<<4096, 256, 0, stream>>>(x2, ln2w, ln2b, h_bf);

    // FC + GELU: [4096,1024] x [4096,1024]^T -> gelu_bf  (256² phase-interleaved)
    gemm8p_fc<<<dim3(16, 16), 512, 0, stream>>>(h_bf, wfc_bf, bfc, gelu_bf);

    // Proj: [4096,4096] x [1024,4096]^T + b_proj + x2 -> out
    gemm_bt<64, 128, 3><<<dim3(64, 8, 1), 256, 0, stream>>>(
        gelu_bf, wproj_bf, 4096, 4096, 4096, 1024, 0, 0,
        bproj, x2, outx, nullptr);
}